// Round 1
// baseline (4703.856 us; speedup 1.0000x reference)
//
#include <hip/hip_runtime.h>
#include <hip/hip_bf16.h>
#include <math.h>

// Problem constants
#define BB 2
#define TT 2048
#define CC 1024
#define NH 16
#define HD 64
#define BT (BB*TT)          // 4096 rows
#define FF_DIM (4*CC)       // 4096
#define LN_EPS 1e-5f
#define ATT_SCALE 0.03125f  // 1/sqrt(1024)  (reference scales by C^-0.5, not head_size)

// ---------------------------------------------------------------------------
// LayerNorm over last dim (C=1024). One block (256 thr) per row, float4 IO.
// ---------------------------------------------------------------------------
__global__ __launch_bounds__(256) void ln_kernel(const float* __restrict__ x,
                                                 const float* __restrict__ g,
                                                 const float* __restrict__ b,
                                                 float* __restrict__ out) {
    int row = blockIdx.x;
    const float4* xr = (const float4*)(x + (size_t)row * CC);
    float4 v = xr[threadIdx.x];
    float s  = v.x + v.y + v.z + v.w;
    float ss = v.x*v.x + v.y*v.y + v.z*v.z + v.w*v.w;
    #pragma unroll
    for (int off = 32; off; off >>= 1) {
        s  += __shfl_down(s, off);
        ss += __shfl_down(ss, off);
    }
    __shared__ float rs_[4], rss_[4];
    __shared__ float mu_s, inv_s;
    int lane = threadIdx.x & 63, wid = threadIdx.x >> 6;
    if (lane == 0) { rs_[wid] = s; rss_[wid] = ss; }
    __syncthreads();
    if (threadIdx.x == 0) {
        float S  = rs_[0] + rs_[1] + rs_[2] + rs_[3];
        float SS = rss_[0] + rss_[1] + rss_[2] + rss_[3];
        float mu  = S * (1.0f / CC);
        float var = SS * (1.0f / CC) - mu * mu;
        mu_s  = mu;
        inv_s = rsqrtf(var + LN_EPS);
    }
    __syncthreads();
    float mu = mu_s, inv = inv_s;
    float4 gv = ((const float4*)g)[threadIdx.x];
    float4 bv = ((const float4*)b)[threadIdx.x];
    float4 o;
    o.x = (v.x - mu) * inv * gv.x + bv.x;
    o.y = (v.y - mu) * inv * gv.y + bv.y;
    o.z = (v.z - mu) * inv * gv.z + bv.z;
    o.w = (v.w - mu) * inv * gv.w + bv.w;
    ((float4*)(out + (size_t)row * CC))[threadIdx.x] = o;
}

// ---------------------------------------------------------------------------
// FP32 tiled GEMM: C[M,N] = A[M,K] @ B[K,N] (+bias) (+relu) (+residual)
// 64x64 tile, BK=16, 256 threads, 4x4 micro-tile per thread.
// M,N,K all multiples of 64/16 here — no bounds checks.
// ---------------------------------------------------------------------------
template<bool BIAS, bool RELU, bool RES>
__global__ __launch_bounds__(256) void gemm_kernel(const float* __restrict__ A,
                                                   const float* __restrict__ Bm,
                                                   const float* __restrict__ bias,
                                                   const float* __restrict__ res,
                                                   float* __restrict__ C,
                                                   int M, int N, int K) {
    __shared__ float As[16][68];   // [k][m], pad to 68 (272B rows, 16B aligned)
    __shared__ float Bs[16][68];   // [k][n]
    int tid = threadIdx.x;
    int tx = tid & 15, ty = tid >> 4;
    int m0 = blockIdx.y * 64, n0 = blockIdx.x * 64;

    int lm  = tid >> 2;          // 0..63 : A tile row
    int lk4 = (tid & 3) * 4;     // 0,4,8,12 : A k sub-block
    int lkB = tid >> 4;          // 0..15 : B tile k row
    int lnB = (tid & 15) * 4;    // B col group

    float acc[4][4] = {};
    for (int kt = 0; kt < K; kt += 16) {
        float4 a = *(const float4*)(A + (size_t)(m0 + lm) * K + kt + lk4);
        As[lk4 + 0][lm] = a.x;
        As[lk4 + 1][lm] = a.y;
        As[lk4 + 2][lm] = a.z;
        As[lk4 + 3][lm] = a.w;
        *(float4*)&Bs[lkB][lnB] =
            *(const float4*)(Bm + (size_t)(kt + lkB) * N + n0 + lnB);
        __syncthreads();
        #pragma unroll
        for (int kk = 0; kk < 16; ++kk) {
            float4 av = *(const float4*)&As[kk][ty * 4];
            float4 bv = *(const float4*)&Bs[kk][tx * 4];
            float a4[4] = {av.x, av.y, av.z, av.w};
            float b4[4] = {bv.x, bv.y, bv.z, bv.w};
            #pragma unroll
            for (int i = 0; i < 4; ++i)
                #pragma unroll
                for (int j = 0; j < 4; ++j)
                    acc[i][j] += a4[i] * b4[j];
        }
        __syncthreads();
    }
    #pragma unroll
    for (int i = 0; i < 4; ++i) {
        int row = m0 + ty * 4 + i;
        #pragma unroll
        for (int j = 0; j < 4; ++j) {
            int col = n0 + tx * 4 + j;
            float vo = acc[i][j];
            if (BIAS) vo += bias[col];
            if (RELU) vo = fmaxf(vo, 0.0f);
            if (RES)  vo += res[(size_t)row * N + col];
            C[(size_t)row * N + col] = vo;
        }
    }
}

// ---------------------------------------------------------------------------
// Causal attention, one block (256 thr) per (query t, head h, batch b).
// q/k/v layout [B,T,H,D] == [B,T,C] with c = h*64+d. Scores in LDS (8 KiB).
// ---------------------------------------------------------------------------
__global__ __launch_bounds__(256) void attn_kernel(const float* __restrict__ q,
                                                   const float* __restrict__ k,
                                                   const float* __restrict__ v,
                                                   float* __restrict__ out) {
    int t = blockIdx.x, h = blockIdx.y, b = blockIdx.z;
    int tid = threadIdx.x;
    __shared__ float sc[TT];
    __shared__ float qs[HD];
    __shared__ float rmax[4], rsum[4];
    __shared__ float rout[4][HD];

    if (tid < HD) qs[tid] = q[((size_t)b * TT + t) * CC + h * HD + tid];
    __syncthreads();

    // Phase 1: scores + local max
    float lmax = -INFINITY;
    for (int kk = tid; kk <= t; kk += 256) {
        const float* kr = k + ((size_t)b * TT + kk) * CC + h * HD;
        float dot = 0.0f;
        #pragma unroll
        for (int d = 0; d < HD; d += 4) {
            float4 k4 = *(const float4*)(kr + d);
            dot += qs[d] * k4.x + qs[d + 1] * k4.y + qs[d + 2] * k4.z + qs[d + 3] * k4.w;
        }
        dot *= ATT_SCALE;
        sc[kk] = dot;
        lmax = fmaxf(lmax, dot);
    }
    #pragma unroll
    for (int off = 32; off; off >>= 1) lmax = fmaxf(lmax, __shfl_down(lmax, off));
    int lane = tid & 63, wid = tid >> 6;
    if (lane == 0) rmax[wid] = lmax;
    __syncthreads();
    float gmax = fmaxf(fmaxf(rmax[0], rmax[1]), fmaxf(rmax[2], rmax[3]));

    // Phase 2: exp + sum
    float lsum = 0.0f;
    for (int kk = tid; kk <= t; kk += 256) {
        float e = __expf(sc[kk] - gmax);
        sc[kk] = e;
        lsum += e;
    }
    #pragma unroll
    for (int off = 32; off; off >>= 1) lsum += __shfl_down(lsum, off);
    if (lane == 0) rsum[wid] = lsum;
    __syncthreads();
    float inv = 1.0f / (rsum[0] + rsum[1] + rsum[2] + rsum[3]);

    // Phase 3: P @ V  (thread -> dim d, 4 k-strides)
    int d = tid & 63, grp = tid >> 6;
    float acc = 0.0f;
    for (int kk = grp; kk <= t; kk += 4)
        acc += sc[kk] * v[((size_t)b * TT + kk) * CC + h * HD + d];
    rout[grp][d] = acc;
    __syncthreads();
    if (tid < HD) {
        float o = (rout[0][tid] + rout[1][tid] + rout[2][tid] + rout[3][tid]) * inv;
        out[((size_t)b * TT + t) * CC + h * HD + tid] = o;
    }
}

// ---------------------------------------------------------------------------
extern "C" void kernel_launch(void* const* d_in, const int* in_sizes, int n_in,
                              void* d_out, int out_size, void* d_ws, size_t ws_size,
                              hipStream_t stream) {
    const float* x   = (const float*)d_in[0];
    const float* Wq  = (const float*)d_in[1];
    const float* Wk  = (const float*)d_in[2];
    const float* Wv  = (const float*)d_in[3];
    const float* Wo  = (const float*)d_in[4];
    const float* bo  = (const float*)d_in[5];
    const float* W1  = (const float*)d_in[6];
    const float* b1  = (const float*)d_in[7];
    const float* W2  = (const float*)d_in[8];
    const float* b2  = (const float*)d_in[9];
    const float* g1  = (const float*)d_in[10];
    const float* be1 = (const float*)d_in[11];
    const float* g2  = (const float*)d_in[12];
    const float* be2 = (const float*)d_in[13];
    float* out = (float*)d_out;

    const size_t S = (size_t)BT * CC;   // 4M floats = 16 MiB
    float* hbuf = (float*)d_ws;         // ln1 out, then ln2 out
    float* qb   = hbuf + S;
    float* kb   = qb + S;
    float* vb   = kb + S;
    float* att  = vb + S;
    float* x2   = att + S;
    float* ff   = x2 + S;               // 4*S floats (64 MiB)

    // ln1
    ln_kernel<<<BT, 256, 0, stream>>>(x, g1, be1, hbuf);
    // q,k,v projections
    dim3 g1024(CC / 64, BT / 64);
    gemm_kernel<false,false,false><<<g1024, 256, 0, stream>>>(hbuf, Wq, nullptr, nullptr, qb, BT, CC, CC);
    gemm_kernel<false,false,false><<<g1024, 256, 0, stream>>>(hbuf, Wk, nullptr, nullptr, kb, BT, CC, CC);
    gemm_kernel<false,false,false><<<g1024, 256, 0, stream>>>(hbuf, Wv, nullptr, nullptr, vb, BT, CC, CC);
    // attention
    attn_kernel<<<dim3(TT, NH, BB), 256, 0, stream>>>(qb, kb, vb, att);
    // out proj + residual -> x2
    gemm_kernel<true,false,true><<<g1024, 256, 0, stream>>>(att, Wo, bo, x, x2, BT, CC, CC);
    // ln2
    ln_kernel<<<BT, 256, 0, stream>>>(x2, g2, be2, hbuf);
    // ffn
    dim3 g4096(FF_DIM / 64, BT / 64);
    gemm_kernel<true,true,false><<<g4096, 256, 0, stream>>>(hbuf, W1, b1, nullptr, ff, BT, FF_DIM, CC);
    gemm_kernel<true,false,true><<<g1024, 256, 0, stream>>>(ff, W2, b2, x2, out, BT, CC, FF_DIM);
}

// Round 2
// 2157.009 us; speedup vs baseline: 2.1807x; 2.1807x over previous
//
#include <hip/hip_runtime.h>
#include <hip/hip_bf16.h>
#include <math.h>

// Problem constants
#define BB 2
#define TT 2048
#define CC 1024
#define NH 16
#define HD 64
#define BT (BB*TT)          // 4096 rows
#define FF_DIM (4*CC)       // 4096
#define LN_EPS 1e-5f
#define ATT_SCALE 0.03125f  // 1/sqrt(1024)  (reference scales by C^-0.5, not head_size)

// ---------------------------------------------------------------------------
// LayerNorm over last dim (C=1024). One block (256 thr) per row, float4 IO.
// ---------------------------------------------------------------------------
__global__ __launch_bounds__(256) void ln_kernel(const float* __restrict__ x,
                                                 const float* __restrict__ g,
                                                 const float* __restrict__ b,
                                                 float* __restrict__ out) {
    int row = blockIdx.x;
    const float4* xr = (const float4*)(x + (size_t)row * CC);
    float4 v = xr[threadIdx.x];
    float s  = v.x + v.y + v.z + v.w;
    float ss = v.x*v.x + v.y*v.y + v.z*v.z + v.w*v.w;
    #pragma unroll
    for (int off = 32; off; off >>= 1) {
        s  += __shfl_down(s, off);
        ss += __shfl_down(ss, off);
    }
    __shared__ float rs_[4], rss_[4];
    __shared__ float mu_s, inv_s;
    int lane = threadIdx.x & 63, wid = threadIdx.x >> 6;
    if (lane == 0) { rs_[wid] = s; rss_[wid] = ss; }
    __syncthreads();
    if (threadIdx.x == 0) {
        float S  = rs_[0] + rs_[1] + rs_[2] + rs_[3];
        float SS = rss_[0] + rss_[1] + rss_[2] + rss_[3];
        float mu  = S * (1.0f / CC);
        float var = SS * (1.0f / CC) - mu * mu;
        mu_s  = mu;
        inv_s = rsqrtf(var + LN_EPS);
    }
    __syncthreads();
    float mu = mu_s, inv = inv_s;
    float4 gv = ((const float4*)g)[threadIdx.x];
    float4 bv = ((const float4*)b)[threadIdx.x];
    float4 o;
    o.x = (v.x - mu) * inv * gv.x + bv.x;
    o.y = (v.y - mu) * inv * gv.y + bv.y;
    o.z = (v.z - mu) * inv * gv.z + bv.z;
    o.w = (v.w - mu) * inv * gv.w + bv.w;
    ((float4*)(out + (size_t)row * CC))[threadIdx.x] = o;
}

// ---------------------------------------------------------------------------
// FP32 tiled GEMM: C[M,N] = A[M,K] @ B[K,N] (+bias) (+relu) (+residual)
// 64x64 tile, BK=16, 256 threads, 4x4 micro-tile per thread.
// ---------------------------------------------------------------------------
template<bool BIAS, bool RELU, bool RES>
__global__ __launch_bounds__(256) void gemm_kernel(const float* __restrict__ A,
                                                   const float* __restrict__ Bm,
                                                   const float* __restrict__ bias,
                                                   const float* __restrict__ res,
                                                   float* __restrict__ C,
                                                   int M, int N, int K) {
    __shared__ float As[16][68];
    __shared__ float Bs[16][68];
    int tid = threadIdx.x;
    int tx = tid & 15, ty = tid >> 4;
    int m0 = blockIdx.y * 64, n0 = blockIdx.x * 64;

    int lm  = tid >> 2;
    int lk4 = (tid & 3) * 4;
    int lkB = tid >> 4;
    int lnB = (tid & 15) * 4;

    float acc[4][4] = {};
    for (int kt = 0; kt < K; kt += 16) {
        float4 a = *(const float4*)(A + (size_t)(m0 + lm) * K + kt + lk4);
        As[lk4 + 0][lm] = a.x;
        As[lk4 + 1][lm] = a.y;
        As[lk4 + 2][lm] = a.z;
        As[lk4 + 3][lm] = a.w;
        *(float4*)&Bs[lkB][lnB] =
            *(const float4*)(Bm + (size_t)(kt + lkB) * N + n0 + lnB);
        __syncthreads();
        #pragma unroll
        for (int kk = 0; kk < 16; ++kk) {
            float4 av = *(const float4*)&As[kk][ty * 4];
            float4 bv = *(const float4*)&Bs[kk][tx * 4];
            float a4[4] = {av.x, av.y, av.z, av.w};
            float b4[4] = {bv.x, bv.y, bv.z, bv.w};
            #pragma unroll
            for (int i = 0; i < 4; ++i)
                #pragma unroll
                for (int j = 0; j < 4; ++j)
                    acc[i][j] += a4[i] * b4[j];
        }
        __syncthreads();
    }
    #pragma unroll
    for (int i = 0; i < 4; ++i) {
        int row = m0 + ty * 4 + i;
        #pragma unroll
        for (int j = 0; j < 4; ++j) {
            int col = n0 + tx * 4 + j;
            float vo = acc[i][j];
            if (BIAS) vo += bias[col];
            if (RELU) vo = fmaxf(vo, 0.0f);
            if (RES)  vo += res[(size_t)row * N + col];
            C[(size_t)row * N + col] = vo;
        }
    }
}

// ---------------------------------------------------------------------------
// Flash-style causal attention. One block (256 thr) per (b, h, 64-query tile).
// K/V tiles staged in LDS; online softmax; per-row (m,l) state replicated in
// registers across the 16-lane column group (shuffle-xor reductions).
// PV uses __shfl broadcast of P fragments (no LDS P tile, 2 syncs/tile).
// ---------------------------------------------------------------------------
__global__ __launch_bounds__(256) void attn_flash_kernel(const float* __restrict__ q,
                                                         const float* __restrict__ k,
                                                         const float* __restrict__ v,
                                                         float* __restrict__ out) {
    const int qt = (int)(gridDim.x - 1) - (int)blockIdx.x;  // heavy tiles first
    const int h = blockIdx.y, b = blockIdx.z;
    const int tid = threadIdx.x;
    const int tx = tid & 15, ty = tid >> 4;   // col group / row group
    const int lane = tid & 63;

    __shared__ float Qt[HD][68];   // [d][q] transposed
    __shared__ float Kt[HD][68];   // [d][k] transposed
    __shared__ float Vs[64][68];   // [k][d] row-major

    const size_t hoff = (size_t)h * HD;
    const float* qbase = q + (size_t)b * TT * CC + hoff;
    const float* kbase = k + (size_t)b * TT * CC + hoff;
    const float* vbase = v + (size_t)b * TT * CC + hoff;

    // Load Q tile transposed. row r = tid>>2 (0..63), d-chunk = (tid&3)*16.
    {
        int r = tid >> 2, dg = (tid & 3) * 16;
        const float* src = qbase + (size_t)(qt * 64 + r) * CC + dg;
        #pragma unroll
        for (int c = 0; c < 16; c += 4) {
            float4 t = *(const float4*)(src + c);
            Qt[dg + c + 0][r] = t.x;
            Qt[dg + c + 1][r] = t.y;
            Qt[dg + c + 2][r] = t.z;
            Qt[dg + c + 3][r] = t.w;
        }
    }

    float O[4][4] = {};
    float m_r[4], l_r[4];
    #pragma unroll
    for (int i = 0; i < 4; ++i) { m_r[i] = -1e30f; l_r[i] = 0.0f; }

    for (int kt = 0; kt <= qt; ++kt) {
        __syncthreads();   // prev tile's reads done before overwriting K/V
        {
            int r = tid >> 2, dg = (tid & 3) * 16;
            const float* ksrc = kbase + (size_t)(kt * 64 + r) * CC + dg;
            #pragma unroll
            for (int c = 0; c < 16; c += 4) {
                float4 t = *(const float4*)(ksrc + c);
                Kt[dg + c + 0][r] = t.x;
                Kt[dg + c + 1][r] = t.y;
                Kt[dg + c + 2][r] = t.z;
                Kt[dg + c + 3][r] = t.w;
            }
            const float* vsrc = vbase + (size_t)(kt * 64 + r) * CC + dg;
            #pragma unroll
            for (int c = 0; c < 16; c += 4)
                *(float4*)&Vs[r][dg + c] = *(const float4*)(vsrc + c);
        }
        __syncthreads();

        // ---- scores: s[4][4] = Q-rows (ty*4..) dot K-cols (tx*4..) ----
        float s[4][4] = {};
        #pragma unroll 8
        for (int d = 0; d < HD; ++d) {
            float4 qv = *(const float4*)&Qt[d][ty * 4];
            float4 kv = *(const float4*)&Kt[d][tx * 4];
            float a4[4] = {qv.x, qv.y, qv.z, qv.w};
            float b4[4] = {kv.x, kv.y, kv.z, kv.w};
            #pragma unroll
            for (int i = 0; i < 4; ++i)
                #pragma unroll
                for (int j = 0; j < 4; ++j)
                    s[i][j] += a4[i] * b4[j];
        }
        // scale + causal mask (only diagonal tile needs masking)
        #pragma unroll
        for (int i = 0; i < 4; ++i)
            #pragma unroll
            for (int j = 0; j < 4; ++j) {
                s[i][j] *= ATT_SCALE;
                if (kt == qt && (tx * 4 + j) > (ty * 4 + i)) s[i][j] = -1e30f;
            }

        // ---- online softmax update ----
        float p[4][4], alpha[4];
        #pragma unroll
        for (int i = 0; i < 4; ++i) {
            float mx = fmaxf(fmaxf(s[i][0], s[i][1]), fmaxf(s[i][2], s[i][3]));
            #pragma unroll
            for (int msk = 1; msk < 16; msk <<= 1)
                mx = fmaxf(mx, __shfl_xor(mx, msk, 64));
            float mnew = fmaxf(m_r[i], mx);
            alpha[i] = __expf(m_r[i] - mnew);
            m_r[i] = mnew;
            float rs = 0.0f;
            #pragma unroll
            for (int j = 0; j < 4; ++j) {
                p[i][j] = __expf(s[i][j] - mnew);
                rs += p[i][j];
            }
            #pragma unroll
            for (int msk = 1; msk < 16; msk <<= 1)
                rs += __shfl_xor(rs, msk, 64);
            l_r[i] = l_r[i] * alpha[i] + rs;
            #pragma unroll
            for (int j = 0; j < 4; ++j) O[i][j] *= alpha[i];
        }

        // ---- PV: O[i][j] += sum_kk P[row_i][kk] * V[kk][col_j] ----
        // P[row][kk] lives in lane ((lane&48) | (kk>>2)) register p[i][kk&3].
        #pragma unroll
        for (int kk = 0; kk < 64; ++kk) {
            int src = (lane & 48) | (kk >> 2);
            float4 vv = *(const float4*)&Vs[kk][tx * 4];
            float pb[4];
            #pragma unroll
            for (int i = 0; i < 4; ++i)
                pb[i] = __shfl(p[i][kk & 3], src, 64);
            float b4[4] = {vv.x, vv.y, vv.z, vv.w};
            #pragma unroll
            for (int i = 0; i < 4; ++i)
                #pragma unroll
                for (int j = 0; j < 4; ++j)
                    O[i][j] += pb[i] * b4[j];
        }
    }

    // ---- epilogue: normalize and store ----
    #pragma unroll
    for (int i = 0; i < 4; ++i) {
        float inv = 1.0f / l_r[i];
        int gq = qt * 64 + ty * 4 + i;
        float4 o;
        o.x = O[i][0] * inv;
        o.y = O[i][1] * inv;
        o.z = O[i][2] * inv;
        o.w = O[i][3] * inv;
        *(float4*)(out + ((size_t)b * TT + gq) * CC + hoff + tx * 4) = o;
    }
}

// ---------------------------------------------------------------------------
extern "C" void kernel_launch(void* const* d_in, const int* in_sizes, int n_in,
                              void* d_out, int out_size, void* d_ws, size_t ws_size,
                              hipStream_t stream) {
    const float* x   = (const float*)d_in[0];
    const float* Wq  = (const float*)d_in[1];
    const float* Wk  = (const float*)d_in[2];
    const float* Wv  = (const float*)d_in[3];
    const float* Wo  = (const float*)d_in[4];
    const float* bo  = (const float*)d_in[5];
    const float* W1  = (const float*)d_in[6];
    const float* b1  = (const float*)d_in[7];
    const float* W2  = (const float*)d_in[8];
    const float* b2  = (const float*)d_in[9];
    const float* g1  = (const float*)d_in[10];
    const float* be1 = (const float*)d_in[11];
    const float* g2  = (const float*)d_in[12];
    const float* be2 = (const float*)d_in[13];
    float* out = (float*)d_out;

    const size_t S = (size_t)BT * CC;
    float* hbuf = (float*)d_ws;
    float* qb   = hbuf + S;
    float* kb   = qb + S;
    float* vb   = kb + S;
    float* att  = vb + S;
    float* x2   = att + S;
    float* ff   = x2 + S;

    ln_kernel<<<BT, 256, 0, stream>>>(x, g1, be1, hbuf);
    dim3 g1024(CC / 64, BT / 64);
    gemm_kernel<false,false,false><<<g1024, 256, 0, stream>>>(hbuf, Wq, nullptr, nullptr, qb, BT, CC, CC);
    gemm_kernel<false,false,false><<<g1024, 256, 0, stream>>>(hbuf, Wk, nullptr, nullptr, kb, BT, CC, CC);
    gemm_kernel<false,false,false><<<g1024, 256, 0, stream>>>(hbuf, Wv, nullptr, nullptr, vb, BT, CC, CC);
    attn_flash_kernel<<<dim3(TT / 64, NH, BB), 256, 0, stream>>>(qb, kb, vb, att);
    gemm_kernel<true,false,true><<<g1024, 256, 0, stream>>>(att, Wo, bo, x, x2, BT, CC, CC);
    ln_kernel<<<BT, 256, 0, stream>>>(x2, g2, be2, hbuf);
    dim3 g4096(FF_DIM / 64, BT / 64);
    gemm_kernel<true,true,false><<<g4096, 256, 0, stream>>>(hbuf, W1, b1, nullptr, ff, BT, FF_DIM, CC);
    gemm_kernel<true,false,true><<<g1024, 256, 0, stream>>>(ff, W2, b2, x2, out, BT, CC, FF_DIM);
}

// Round 3
// 502.602 us; speedup vs baseline: 9.3590x; 4.2917x over previous
//
#include <hip/hip_runtime.h>
#include <hip/hip_bf16.h>
#include <math.h>

#define BB 2
#define TT 2048
#define CC 1024
#define NH 16
#define HD 64
#define BT (BB*TT)          // 4096 rows
#define LN_EPS 1e-5f
#define ATT_SCALE 0.03125f  // C^-0.5 (reference scales by full C, not head_size)

typedef __bf16 bf16x8 __attribute__((ext_vector_type(8)));
typedef __bf16 bf16x4 __attribute__((ext_vector_type(4)));
typedef float floatx4 __attribute__((ext_vector_type(4)));

__device__ __forceinline__ void gl_lds16(const __bf16* g, __bf16* l) {
    __builtin_amdgcn_global_load_lds((const __attribute__((address_space(1))) void*)g,
                                     (__attribute__((address_space(3))) void*)l,
                                     16, 0, 0);
}

// ---------------------------------------------------------------------------
// LayerNorm: fp32 in -> bf16 out. One block (256 thr) per row.
// ---------------------------------------------------------------------------
__global__ __launch_bounds__(256) void ln_kernel(const float* __restrict__ x,
                                                 const float* __restrict__ g,
                                                 const float* __restrict__ b,
                                                 __bf16* __restrict__ out) {
    int row = blockIdx.x;
    const float4* xr = (const float4*)(x + (size_t)row * CC);
    float4 v = xr[threadIdx.x];
    float s  = v.x + v.y + v.z + v.w;
    float ss = v.x*v.x + v.y*v.y + v.z*v.z + v.w*v.w;
    #pragma unroll
    for (int off = 32; off; off >>= 1) {
        s  += __shfl_down(s, off);
        ss += __shfl_down(ss, off);
    }
    __shared__ float rs_[4], rss_[4];
    __shared__ float mu_s, inv_s;
    int lane = threadIdx.x & 63, wid = threadIdx.x >> 6;
    if (lane == 0) { rs_[wid] = s; rss_[wid] = ss; }
    __syncthreads();
    if (threadIdx.x == 0) {
        float S  = rs_[0] + rs_[1] + rs_[2] + rs_[3];
        float SS = rss_[0] + rss_[1] + rss_[2] + rss_[3];
        float mu  = S * (1.0f / CC);
        float var = SS * (1.0f / CC) - mu * mu;
        mu_s  = mu;
        inv_s = rsqrtf(var + LN_EPS);
    }
    __syncthreads();
    float mu = mu_s, inv = inv_s;
    float4 gv = ((const float4*)g)[threadIdx.x];
    float4 bv = ((const float4*)b)[threadIdx.x];
    bf16x4 o;
    o[0] = (__bf16)((v.x - mu) * inv * gv.x + bv.x);
    o[1] = (__bf16)((v.y - mu) * inv * gv.y + bv.y);
    o[2] = (__bf16)((v.z - mu) * inv * gv.z + bv.z);
    o[3] = (__bf16)((v.w - mu) * inv * gv.w + bv.w);
    *(bf16x4*)(out + (size_t)row * CC + threadIdx.x * 4) = o;
}

// ---------------------------------------------------------------------------
// Weight transpose + convert: W[K][N] fp32 -> Wt[N][K] bf16. 32x32 tiles.
// ---------------------------------------------------------------------------
__global__ __launch_bounds__(256) void transpose_w(const float* __restrict__ W,
                                                   __bf16* __restrict__ Wt,
                                                   int K, int N) {
    __shared__ float t[32][33];
    int n0 = blockIdx.x * 32, k0 = blockIdx.y * 32;
    int tx = threadIdx.x & 31, ty = threadIdx.x >> 5;
    #pragma unroll
    for (int r = ty; r < 32; r += 8)
        t[r][tx] = W[(size_t)(k0 + r) * N + n0 + tx];
    __syncthreads();
    #pragma unroll
    for (int r = ty; r < 32; r += 8)
        Wt[(size_t)(n0 + r) * K + k0 + tx] = (__bf16)t[tx][r];
}

// ---------------------------------------------------------------------------
// bf16 MFMA GEMM (m97 structure): C[M,N] = A[M,K] @ Bt[N,K]^T (+bias/relu/res)
// 128x128 tile, BK=32, 256 thr (4 waves, 2x2 of 64x64), 16x16x32 MFMA.
// ---------------------------------------------------------------------------
template<typename OT, bool BIAS, bool RELU, bool RES>
__global__ __launch_bounds__(256) void gemm_bf16(const __bf16* __restrict__ A,
                                                 const __bf16* __restrict__ Bt,
                                                 const float* __restrict__ bias,
                                                 const float* __restrict__ res,
                                                 OT* __restrict__ C,
                                                 int M, int N, int K) {
    __shared__ __bf16 As[128 * 32];
    __shared__ __bf16 Bs[128 * 32];
    const int tid = threadIdx.x;
    const int l = tid & 63, w = tid >> 6;
    const int wm = w >> 1, wn = w & 1;
    const int m0 = blockIdx.y * 128, n0 = blockIdx.x * 128;

    // staging: call c covers rows c*64 + w*16 + (l>>2), k-chunk (l&3)*8
    const int srow = w * 16 + (l >> 2);
    const int skof = (l & 3) * 8;
    const __bf16* ga = A  + (size_t)(m0 + srow) * K + skof;
    const __bf16* gb = Bt + (size_t)(n0 + srow) * K + skof;
    __bf16* la0 = As + w * 512;   // wave-uniform LDS base; HW adds lane*16B
    __bf16* lb0 = Bs + w * 512;

    floatx4 acc[4][4];
    #pragma unroll
    for (int i = 0; i < 4; ++i)
        #pragma unroll
        for (int j = 0; j < 4; ++j) {
            floatx4 z = {0.f, 0.f, 0.f, 0.f};
            acc[i][j] = z;
        }

    for (int kt = 0; kt < K; kt += 32) {
        __syncthreads();
        gl_lds16(ga,                   la0);
        gl_lds16(ga + (size_t)64 * K,  la0 + 2048);
        gl_lds16(gb,                   lb0);
        gl_lds16(gb + (size_t)64 * K,  lb0 + 2048);
        ga += 32; gb += 32;
        __syncthreads();

        bf16x8 af[4], bfr[4];
        #pragma unroll
        for (int i = 0; i < 4; ++i)
            af[i] = *(const bf16x8*)&As[(wm * 64 + i * 16 + (l & 15)) * 32 + (l >> 4) * 8];
        #pragma unroll
        for (int j = 0; j < 4; ++j)
            bfr[j] = *(const bf16x8*)&Bs[(wn * 64 + j * 16 + (l & 15)) * 32 + (l >> 4) * 8];
        #pragma unroll
        for (int i = 0; i < 4; ++i)
            #pragma unroll
            for (int j = 0; j < 4; ++j)
                acc[i][j] = __builtin_amdgcn_mfma_f32_16x16x32_bf16(af[i], bfr[j], acc[i][j], 0, 0, 0);
    }

    #pragma unroll
    for (int i = 0; i < 4; ++i) {
        int row = m0 + wm * 64 + i * 16 + (l >> 4) * 4;
        #pragma unroll
        for (int j = 0; j < 4; ++j) {
            int col = n0 + wn * 64 + j * 16 + (l & 15);
            float bv = BIAS ? bias[col] : 0.0f;
            #pragma unroll
            for (int r = 0; r < 4; ++r) {
                float vo = acc[i][j][r] + bv;
                if (RELU) vo = fmaxf(vo, 0.0f);
                if (RES)  vo += res[(size_t)(row + r) * N + col];
                C[(size_t)(row + r) * N + col] = (OT)vo;
            }
        }
    }
}

// ---------------------------------------------------------------------------
// MFMA flash attention. qkv: [BT][3072] bf16 (q|k|v each head-major h*64+d).
// One block per (b, h, 64-q-tile); 4 waves x 16 q-rows. Online softmax in
// C-layout regs; P -> per-wave LDS -> A-layout; PV vs V^T in LDS.
// ---------------------------------------------------------------------------
__global__ __launch_bounds__(256) void attn_mfma(const __bf16* __restrict__ qkv,
                                                 __bf16* __restrict__ att) {
    const int qt = 31 - (int)blockIdx.x;   // heavy tiles first
    const int h = blockIdx.y, b = blockIdx.z;
    const int tid = threadIdx.x;
    const int l = tid & 63, w = tid >> 6;

    __shared__ __bf16 Ks[64 * 64];      // [key][d]
    __shared__ __bf16 Vt[64 * 72];      // [d][key], padded rows (144B)
    __shared__ __bf16 Ps[4][16 * 72];   // per-wave P tile [qrow][key]

    const size_t base = (size_t)b * TT * 3072 + (size_t)h * HD;
    const __bf16* qp = qkv + base;
    const __bf16* kp = qkv + base + 1024;
    const __bf16* vp = qkv + base + 2048;

    // Q A-frags, kept in registers for the whole block
    const int qrowA = qt * 64 + w * 16 + (l & 15);
    bf16x8 qa0 = *(const bf16x8*)(qp + (size_t)qrowA * 3072 + (l >> 4) * 8);
    bf16x8 qa1 = *(const bf16x8*)(qp + (size_t)qrowA * 3072 + 32 + (l >> 4) * 8);

    floatx4 O[4];
    float m_r[4], l_r[4];
    #pragma unroll
    for (int jd = 0; jd < 4; ++jd) {
        floatx4 z = {0.f, 0.f, 0.f, 0.f};
        O[jd] = z;
    }
    #pragma unroll
    for (int r = 0; r < 4; ++r) { m_r[r] = -1e30f; l_r[r] = 0.0f; }

    // staging thread mappings
    const int krow = w * 8 + (l >> 3);       // + c*32
    const int kdo  = (l & 7) * 8;
    const int vr = tid >> 2, vdc = (tid & 3) * 16;

    const int qrow_c = qt * 64 + w * 16 + (l >> 4) * 4;  // + r

    for (int kt = 0; kt <= qt; ++kt) {
        __syncthreads();
        // K tile via async global->LDS (wave-uniform base + lane*16B)
        gl_lds16(kp + (size_t)(kt * 64 + krow) * 3072 + kdo,      Ks + w * 512);
        gl_lds16(kp + (size_t)(kt * 64 + 32 + krow) * 3072 + kdo, Ks + 2048 + w * 512);
        // V tile transposed into Vt[d][key]
        {
            const __bf16* vsrc = vp + (size_t)(kt * 64 + vr) * 3072 + vdc;
            bf16x8 v0 = *(const bf16x8*)vsrc;
            bf16x8 v1 = *(const bf16x8*)(vsrc + 8);
            #pragma unroll
            for (int i = 0; i < 8; ++i) Vt[(vdc + i) * 72 + vr]     = v0[i];
            #pragma unroll
            for (int i = 0; i < 8; ++i) Vt[(vdc + 8 + i) * 72 + vr] = v1[i];
        }
        __syncthreads();

        // S = Q K^T  (4 key-subtiles of 16)
        floatx4 S[4];
        #pragma unroll
        for (int j = 0; j < 4; ++j) {
            bf16x8 kb0 = *(const bf16x8*)&Ks[(j * 16 + (l & 15)) * 64 + (l >> 4) * 8];
            bf16x8 kb1 = *(const bf16x8*)&Ks[(j * 16 + (l & 15)) * 64 + 32 + (l >> 4) * 8];
            floatx4 z = {0.f, 0.f, 0.f, 0.f};
            z = __builtin_amdgcn_mfma_f32_16x16x32_bf16(qa0, kb0, z, 0, 0, 0);
            S[j] = __builtin_amdgcn_mfma_f32_16x16x32_bf16(qa1, kb1, z, 0, 0, 0);
        }

        // online softmax (per output row r; row data spread over 16-lane group)
        #pragma unroll
        for (int r = 0; r < 4; ++r) {
            float sj[4];
            #pragma unroll
            for (int j = 0; j < 4; ++j) {
                sj[j] = S[j][r] * ATT_SCALE;
                if (kt == qt && (kt * 64 + j * 16 + (l & 15)) > (qrow_c + r))
                    sj[j] = -1e30f;
            }
            float mx = fmaxf(fmaxf(sj[0], sj[1]), fmaxf(sj[2], sj[3]));
            #pragma unroll
            for (int msk = 1; msk < 16; msk <<= 1)
                mx = fmaxf(mx, __shfl_xor(mx, msk, 64));
            float mnew = fmaxf(m_r[r], mx);
            float alpha = __expf(m_r[r] - mnew);
            m_r[r] = mnew;
            float rs = 0.0f;
            float p[4];
            #pragma unroll
            for (int j = 0; j < 4; ++j) {
                p[j] = __expf(sj[j] - mnew);
                rs += p[j];
            }
            #pragma unroll
            for (int msk = 1; msk < 16; msk <<= 1)
                rs += __shfl_xor(rs, msk, 64);
            l_r[r] = l_r[r] * alpha + rs;
            #pragma unroll
            for (int jd = 0; jd < 4; ++jd) O[jd][r] *= alpha;
            // stash P into per-wave LDS tile (C-layout -> [qrow][key])
            #pragma unroll
            for (int j = 0; j < 4; ++j)
                Ps[w][((l >> 4) * 4 + r) * 72 + j * 16 + (l & 15)] = (__bf16)p[j];
        }

        // PV: O += P @ V   (P from LDS in A-layout, V^T B-frags contiguous)
        bf16x8 pa0 = *(const bf16x8*)&Ps[w][(l & 15) * 72 + (l >> 4) * 8];
        bf16x8 pa1 = *(const bf16x8*)&Ps[w][(l & 15) * 72 + 32 + (l >> 4) * 8];
        #pragma unroll
        for (int jd = 0; jd < 4; ++jd) {
            bf16x8 vb0 = *(const bf16x8*)&Vt[(jd * 16 + (l & 15)) * 72 + (l >> 4) * 8];
            bf16x8 vb1 = *(const bf16x8*)&Vt[(jd * 16 + (l & 15)) * 72 + 32 + (l >> 4) * 8];
            O[jd] = __builtin_amdgcn_mfma_f32_16x16x32_bf16(pa0, vb0, O[jd], 0, 0, 0);
            O[jd] = __builtin_amdgcn_mfma_f32_16x16x32_bf16(pa1, vb1, O[jd], 0, 0, 0);
        }
    }

    // epilogue: normalize, store bf16
    #pragma unroll
    for (int r = 0; r < 4; ++r) {
        float inv = 1.0f / l_r[r];
        int qg = qrow_c + r;
        #pragma unroll
        for (int jd = 0; jd < 4; ++jd)
            att[((size_t)b * TT + qg) * CC + h * HD + jd * 16 + (l & 15)] =
                (__bf16)(O[jd][r] * inv);
    }
}

// ---------------------------------------------------------------------------
extern "C" void kernel_launch(void* const* d_in, const int* in_sizes, int n_in,
                              void* d_out, int out_size, void* d_ws, size_t ws_size,
                              hipStream_t stream) {
    const float* x   = (const float*)d_in[0];
    const float* Wq  = (const float*)d_in[1];
    const float* Wk  = (const float*)d_in[2];
    const float* Wv  = (const float*)d_in[3];
    const float* Wo  = (const float*)d_in[4];
    const float* bo  = (const float*)d_in[5];
    const float* W1  = (const float*)d_in[6];
    const float* b1  = (const float*)d_in[7];
    const float* W2  = (const float*)d_in[8];
    const float* b2  = (const float*)d_in[9];
    const float* g1  = (const float*)d_in[10];
    const float* be1 = (const float*)d_in[11];
    const float* g2  = (const float*)d_in[12];
    const float* be2 = (const float*)d_in[13];
    float* out = (float*)d_out;

    char* p = (char*)d_ws;
    __bf16* hb    = (__bf16*)p; p += (size_t)BT * CC * 2;        // ln out
    __bf16* qkvb  = (__bf16*)p; p += (size_t)BT * 3072 * 2;      // q|k|v
    __bf16* attb  = (__bf16*)p; p += (size_t)BT * CC * 2;        // attn out
    float*  x2    = (float*)p;  p += (size_t)BT * CC * 4;        // resid 1
    __bf16* ffb   = (__bf16*)p; p += (size_t)BT * 4096 * 2;      // ffn mid
    __bf16* WqkvT = (__bf16*)p; p += (size_t)3072 * 1024 * 2;
    __bf16* WoT   = (__bf16*)p; p += (size_t)1024 * 1024 * 2;
    __bf16* W1T   = (__bf16*)p; p += (size_t)4096 * 1024 * 2;
    __bf16* W2T   = (__bf16*)p; p += (size_t)1024 * 4096 * 2;

    // weight transpose+convert (fp32 [K][N] -> bf16 [N][K])
    transpose_w<<<dim3(32, 32), 256, 0, stream>>>(Wq, WqkvT,                 1024, 1024);
    transpose_w<<<dim3(32, 32), 256, 0, stream>>>(Wk, WqkvT + 1024 * 1024,   1024, 1024);
    transpose_w<<<dim3(32, 32), 256, 0, stream>>>(Wv, WqkvT + 2048 * 1024,   1024, 1024);
    transpose_w<<<dim3(32, 32), 256, 0, stream>>>(Wo, WoT,                   1024, 1024);
    transpose_w<<<dim3(128, 32), 256, 0, stream>>>(W1, W1T,                  1024, 4096);
    transpose_w<<<dim3(32, 128), 256, 0, stream>>>(W2, W2T,                  4096, 1024);

    // ln1 -> bf16
    ln_kernel<<<BT, 256, 0, stream>>>(x, g1, be1, hb);
    // fused QKV projection: [4096,1024] @ [1024,3072]
    gemm_bf16<__bf16, false, false, false><<<dim3(24, 32), 256, 0, stream>>>(
        hb, WqkvT, nullptr, nullptr, qkvb, BT, 3072, 1024);
    // attention
    attn_mfma<<<dim3(32, NH, BB), 256, 0, stream>>>(qkvb, attb);
    // out proj + bias + residual(x) -> x2 (fp32)
    gemm_bf16<float, true, false, true><<<dim3(8, 32), 256, 0, stream>>>(
        attb, WoT, bo, x, x2, BT, 1024, 1024);
    // ln2 -> bf16
    ln_kernel<<<BT, 256, 0, stream>>>(x2, g2, be2, hb);
    // ffn1 + bias + relu -> bf16
    gemm_bf16<__bf16, true, true, false><<<dim3(32, 32), 256, 0, stream>>>(
        hb, W1T, b1, nullptr, ffb, BT, 4096, 1024);
    // ffn2 + bias + residual(x2) -> out (fp32)
    gemm_bf16<float, true, false, true><<<dim3(8, 32), 256, 0, stream>>>(
        ffb, W2T, b2, x2, out, BT, 1024, 4096);
}

// Round 4
// 398.930 us; speedup vs baseline: 11.7912x; 1.2599x over previous
//
#include <hip/hip_runtime.h>
#include <hip/hip_bf16.h>
#include <math.h>

#define BB 2
#define TT 2048
#define CC 1024
#define NH 16
#define HD 64
#define BT (BB*TT)          // 4096 rows
#define LN_EPS 1e-5f
#define ATT_SCALE 0.03125f  // C^-0.5 (reference scales by full C, not head_size)

typedef __bf16 bf16x8 __attribute__((ext_vector_type(8)));
typedef __bf16 bf16x4 __attribute__((ext_vector_type(4)));
typedef short shortx4 __attribute__((ext_vector_type(4)));
typedef float floatx4 __attribute__((ext_vector_type(4)));

__device__ __forceinline__ void gl_lds16(const __bf16* g, __bf16* l) {
    __builtin_amdgcn_global_load_lds((const __attribute__((address_space(1))) void*)g,
                                     (__attribute__((address_space(3))) void*)l,
                                     16, 0, 0);
}

#define MFMA32(a, b, c) __builtin_amdgcn_mfma_f32_16x16x32_bf16(a, b, c, 0, 0, 0)

#if __has_builtin(__builtin_amdgcn_mfma_f32_16x16x16_bf16)
__device__ __forceinline__ floatx4 mfma16(bf16x4 a, bf16x4 b, floatx4 c) {
    return __builtin_amdgcn_mfma_f32_16x16x16_bf16(a, b, c, 0, 0, 0);
}
#else
__device__ __forceinline__ floatx4 mfma16(bf16x4 a, bf16x4 b, floatx4 c) {
    return __builtin_amdgcn_mfma_f32_16x16x16bf16_1k(
        __builtin_bit_cast(shortx4, a), __builtin_bit_cast(shortx4, b), c, 0, 0, 0);
}
#endif

// ---------------------------------------------------------------------------
// LayerNorm: fp32 in -> bf16 out. One block (256 thr) per row.
// ---------------------------------------------------------------------------
__global__ __launch_bounds__(256) void ln_kernel(const float* __restrict__ x,
                                                 const float* __restrict__ g,
                                                 const float* __restrict__ b,
                                                 __bf16* __restrict__ out) {
    int row = blockIdx.x;
    const float4* xr = (const float4*)(x + (size_t)row * CC);
    float4 v = xr[threadIdx.x];
    float s  = v.x + v.y + v.z + v.w;
    float ss = v.x*v.x + v.y*v.y + v.z*v.z + v.w*v.w;
    #pragma unroll
    for (int off = 32; off; off >>= 1) {
        s  += __shfl_down(s, off);
        ss += __shfl_down(ss, off);
    }
    __shared__ float rs_[4], rss_[4];
    __shared__ float mu_s, inv_s;
    int lane = threadIdx.x & 63, wid = threadIdx.x >> 6;
    if (lane == 0) { rs_[wid] = s; rss_[wid] = ss; }
    __syncthreads();
    if (threadIdx.x == 0) {
        float S  = rs_[0] + rs_[1] + rs_[2] + rs_[3];
        float SS = rss_[0] + rss_[1] + rss_[2] + rss_[3];
        float mu  = S * (1.0f / CC);
        float var = SS * (1.0f / CC) - mu * mu;
        mu_s  = mu;
        inv_s = rsqrtf(var + LN_EPS);
    }
    __syncthreads();
    float mu = mu_s, inv = inv_s;
    float4 gv = ((const float4*)g)[threadIdx.x];
    float4 bv = ((const float4*)b)[threadIdx.x];
    bf16x4 o;
    o[0] = (__bf16)((v.x - mu) * inv * gv.x + bv.x);
    o[1] = (__bf16)((v.y - mu) * inv * gv.y + bv.y);
    o[2] = (__bf16)((v.z - mu) * inv * gv.z + bv.z);
    o[3] = (__bf16)((v.w - mu) * inv * gv.w + bv.w);
    *(bf16x4*)(out + (size_t)row * CC + threadIdx.x * 4) = o;
}

// ---------------------------------------------------------------------------
// All weight transposes fused in one launch. 32x32 tiles; block-uniform branch.
// ---------------------------------------------------------------------------
__global__ __launch_bounds__(256) void transpose_all(
        const float* __restrict__ Wq, const float* __restrict__ Wk,
        const float* __restrict__ Wv, const float* __restrict__ Wo,
        const float* __restrict__ W1, const float* __restrict__ W2,
        __bf16* __restrict__ WqkvT, __bf16* __restrict__ WoT,
        __bf16* __restrict__ W1T, __bf16* __restrict__ W2T) {
    int idx = blockIdx.x;
    const float* src; __bf16* dst; int K, N, tn, tk;
    if (idx < 3072) {                      // Wq|Wk|Wv -> WqkvT (stacked)
        int wsel = idx >> 10, local = idx & 1023;
        src = (wsel == 0) ? Wq : (wsel == 1 ? Wk : Wv);
        dst = WqkvT + (size_t)wsel * 1024 * 1024;
        K = 1024; N = 1024; tn = local & 31; tk = local >> 5;
    } else if (idx < 4096) {
        int local = idx - 3072;
        src = Wo; dst = WoT; K = 1024; N = 1024; tn = local & 31; tk = local >> 5;
    } else if (idx < 8192) {
        int local = idx - 4096;
        src = W1; dst = W1T; K = 1024; N = 4096; tn = local & 127; tk = local >> 7;
    } else {
        int local = idx - 8192;
        src = W2; dst = W2T; K = 4096; N = 1024; tn = local & 31; tk = local >> 5;
    }
    __shared__ float t[32][33];
    int n0 = tn * 32, k0 = tk * 32;
    int tx = threadIdx.x & 31, ty = threadIdx.x >> 5;
    #pragma unroll
    for (int r = ty; r < 32; r += 8)
        t[r][tx] = src[(size_t)(k0 + r) * N + n0 + tx];
    __syncthreads();
    #pragma unroll
    for (int r = ty; r < 32; r += 8)
        dst[(size_t)(n0 + r) * K + k0 + tx] = (__bf16)t[tx][r];
}

// ---------------------------------------------------------------------------
// bf16 MFMA GEMM: C[M,N] = A[M,K] @ Bt[N,K]^T (+bias/relu/res).
// Tile 128 x NT (NT=128 or 64), BK=32, 256 thr. VSPLIT: for col>=2048 the
// output (V of QKV) is written TRANSPOSED per head into vt[(b*16+h)*64+d][t].
// ---------------------------------------------------------------------------
template<int NT, typename OT, bool BIAS, bool RELU, bool RES, bool VSPLIT>
__global__ __launch_bounds__(256) void gemm_bf16(const __bf16* __restrict__ A,
                                                 const __bf16* __restrict__ Bt,
                                                 const float* __restrict__ bias,
                                                 const float* __restrict__ res,
                                                 OT* __restrict__ C,
                                                 __bf16* __restrict__ vt,
                                                 int M, int N, int K) {
    constexpr int JN = NT / 32;
    __shared__ __bf16 As[128 * 32];
    __shared__ __bf16 Bs[NT * 32];
    const int tid = threadIdx.x;
    const int l = tid & 63, w = tid >> 6;
    const int m = l & 15, g = l >> 4;
    const int wm = w >> 1, wn = w & 1;
    const int m0 = blockIdx.y * 128, n0 = blockIdx.x * NT;

    const int srow = w * 16 + (l >> 2);
    const int skof = (l & 3) * 8;
    const __bf16* ga = A  + (size_t)(m0 + srow) * K + skof;
    const __bf16* gb = Bt + (size_t)(n0 + srow) * K + skof;
    __bf16* la0 = As + w * 512;
    __bf16* lb0 = Bs + w * 512;

    floatx4 acc[4][JN];
    #pragma unroll
    for (int i = 0; i < 4; ++i)
        #pragma unroll
        for (int j = 0; j < JN; ++j) {
            floatx4 z = {0.f, 0.f, 0.f, 0.f};
            acc[i][j] = z;
        }

    for (int kt = 0; kt < K; kt += 32) {
        __syncthreads();
        gl_lds16(ga,                  la0);
        gl_lds16(ga + (size_t)64 * K, la0 + 2048);
        gl_lds16(gb,                  lb0);
        if (NT == 128)
            gl_lds16(gb + (size_t)64 * K, lb0 + 2048);
        ga += 32; gb += 32;
        __syncthreads();

        bf16x8 af[4], bfr[JN];
        #pragma unroll
        for (int i = 0; i < 4; ++i)
            af[i] = *(const bf16x8*)&As[(wm * 64 + i * 16 + m) * 32 + g * 8];
        #pragma unroll
        for (int j = 0; j < JN; ++j)
            bfr[j] = *(const bf16x8*)&Bs[(wn * (NT / 2) + j * 16 + m) * 32 + g * 8];
        #pragma unroll
        for (int i = 0; i < 4; ++i)
            #pragma unroll
            for (int j = 0; j < JN; ++j)
                acc[i][j] = MFMA32(af[i], bfr[j], acc[i][j]);
    }

    if (VSPLIT && n0 >= 2048) {
        // V columns: write transposed per-head into vt [(b*16+h)*64+d][2048]
        #pragma unroll
        for (int i = 0; i < 4; ++i) {
            int row = m0 + wm * 64 + i * 16 + g * 4;
            int bb = row >> 11, t0 = row & 2047;
            #pragma unroll
            for (int j = 0; j < JN; ++j) {
                int cv = n0 + wn * (NT / 2) + j * 16 + m - 2048;
                bf16x4 o;
                #pragma unroll
                for (int r = 0; r < 4; ++r) o[r] = (__bf16)acc[i][j][r];
                *(bf16x4*)(vt + ((size_t)(bb * NH + (cv >> 6)) * HD + (cv & 63)) * 2048 + t0) = o;
            }
        }
    } else {
        #pragma unroll
        for (int i = 0; i < 4; ++i) {
            int row = m0 + wm * 64 + i * 16 + g * 4;
            #pragma unroll
            for (int j = 0; j < JN; ++j) {
                int col = n0 + wn * (NT / 2) + j * 16 + m;
                float bv = BIAS ? bias[col] : 0.0f;
                #pragma unroll
                for (int r = 0; r < 4; ++r) {
                    float vo = acc[i][j][r] + bv;
                    if (RELU) vo = fmaxf(vo, 0.0f);
                    if (RES)  vo += res[(size_t)(row + r) * N + col];
                    C[(size_t)(row + r) * N + col] = (OT)vo;
                }
            }
        }
    }
}

// ---------------------------------------------------------------------------
// Flash attention, S^T orientation. One block per (b, h, 128-q-tile); 4 waves,
// each wave owns 32 q-rows (2 n-tiles). S^T = K·Q^T puts qrow = lane&15 so
// softmax rows live in-lane (2 shfl_xor per reduction) and P is directly in
// the B-operand layout of mfma_16x16x16 (k = 4*(l>>4)+j == key%16). PV uses
// V^T staged from global vt (pre-transposed by QKV epilogue). No P LDS trip.
// ---------------------------------------------------------------------------
__global__ __launch_bounds__(256, 2) void attn_mfma2(const __bf16* __restrict__ qkv,
                                                     const __bf16* __restrict__ vt,
                                                     __bf16* __restrict__ att) {
    const int qt = 15 - (int)blockIdx.x;   // heavy tiles first
    const int h = blockIdx.y, b = blockIdx.z;
    const int tid = threadIdx.x;
    const int l = tid & 63, w = tid >> 6;
    const int m = l & 15, g = l >> 4;

    __shared__ __bf16 Ks[2][128][32];   // [d-half][key][32 d]   16 KB
    __shared__ __bf16 Vt3[8][64][16];   // [key/16][d][16 keys]  16 KB

    const __bf16* qp = qkv + (size_t)b * TT * 3072 + h * HD;
    const __bf16* kp = qp + 1024;
    const __bf16* vh = vt + (size_t)(b * NH + h) * HD * 2048;

    // Q fragments (B-operand): lane n = qrow, k = d
    bf16x8 qb[2][2];
    #pragma unroll
    for (int nt = 0; nt < 2; ++nt) {
        int qrow = qt * 128 + w * 32 + nt * 16 + m;
        qb[nt][0] = *(const bf16x8*)(qp + (size_t)qrow * 3072 + g * 8);
        qb[nt][1] = *(const bf16x8*)(qp + (size_t)qrow * 3072 + 32 + g * 8);
    }

    floatx4 O[2][4];
    float m_s[2], l_s[2];
    #pragma unroll
    for (int nt = 0; nt < 2; ++nt) {
        #pragma unroll
        for (int jd = 0; jd < 4; ++jd) {
            floatx4 z = {0.f, 0.f, 0.f, 0.f};
            O[nt][jd] = z;
        }
        m_s[nt] = -1e30f; l_s[nt] = 0.0f;
    }

    for (int kt = 0; kt <= qt; ++kt) {
        __syncthreads();
        // stage K tile: 4 calls/wave, chunk idx = w*4+c -> (dhalf, 16-key grp)
        #pragma unroll
        for (int c = 0; c < 4; ++c) {
            int idx = w * 4 + c;
            int dh = idx >> 3, k16 = idx & 7;
            gl_lds16(kp + (size_t)(kt * 128 + k16 * 16 + (l >> 2)) * 3072 + dh * 32 + (l & 3) * 8,
                     (__bf16*)Ks + dh * 4096 + k16 * 512);
        }
        // stage V^T tile: 4 calls/wave, chunk idx -> (jt, d-half)
        #pragma unroll
        for (int c = 0; c < 4; ++c) {
            int idx = w * 4 + c;
            int jt = idx >> 1, dhf = idx & 1;
            gl_lds16(vh + (size_t)(dhf * 32 + (l >> 1)) * 2048 + kt * 128 + jt * 16 + (l & 1) * 8,
                     (__bf16*)Vt3 + jt * 1024 + dhf * 512);
        }
        __syncthreads();

        // S^T[key][qrow] = K·Q^T  (8 key-subtiles x 2 d-halves)
        floatx4 S[2][8];
        #pragma unroll
        for (int jt = 0; jt < 8; ++jt) {
            bf16x8 kf0 = *(const bf16x8*)&Ks[0][jt * 16 + m][g * 8];
            bf16x8 kf1 = *(const bf16x8*)&Ks[1][jt * 16 + m][g * 8];
            #pragma unroll
            for (int nt = 0; nt < 2; ++nt) {
                floatx4 z = {0.f, 0.f, 0.f, 0.f};
                z = MFMA32(kf0, qb[nt][0], z);
                S[nt][jt] = MFMA32(kf1, qb[nt][1], z);
            }
        }

        // online softmax; lane owns qrow = l&15 (per nt), key = 16jt+4g+r
        bf16x4 pv[2][8];
        const bool last = (kt == qt);
        #pragma unroll
        for (int nt = 0; nt < 2; ++nt) {
            if (last) {
                int qr = w * 32 + nt * 16 + m;   // q-row rel. to tile
                #pragma unroll
                for (int jt = 0; jt < 8; ++jt)
                    #pragma unroll
                    for (int r = 0; r < 4; ++r)
                        if (jt * 16 + g * 4 + r > qr) S[nt][jt][r] = -1e30f;
            }
            float mx = -1e30f;
            #pragma unroll
            for (int jt = 0; jt < 8; ++jt)
                #pragma unroll
                for (int r = 0; r < 4; ++r)
                    mx = fmaxf(mx, S[nt][jt][r]);
            mx = fmaxf(mx, __shfl_xor(mx, 16, 64));
            mx = fmaxf(mx, __shfl_xor(mx, 32, 64));
            float mnew = fmaxf(m_s[nt], mx);
            float alpha = __expf((m_s[nt] - mnew) * ATT_SCALE);
            m_s[nt] = mnew;
            float mc = mnew * ATT_SCALE;
            float ls = 0.0f;
            #pragma unroll
            for (int jt = 0; jt < 8; ++jt) {
                bf16x4 t;
                #pragma unroll
                for (int r = 0; r < 4; ++r) {
                    float p = __expf(fmaf(S[nt][jt][r], ATT_SCALE, -mc));
                    ls += p;
                    t[r] = (__bf16)p;
                }
                pv[nt][jt] = t;
            }
            ls += __shfl_xor(ls, 16, 64);
            ls += __shfl_xor(ls, 32, 64);
            l_s[nt] = l_s[nt] * alpha + ls;
            #pragma unroll
            for (int jd = 0; jd < 4; ++jd) O[nt][jd] *= alpha;
        }

        // O^T[d][qrow] += V^T · P   (x16 MFMA: P already in B layout, in-lane)
        #pragma unroll
        for (int jt = 0; jt < 8; ++jt)
            #pragma unroll
            for (int jd = 0; jd < 4; ++jd) {
                bf16x4 vf = *(const bf16x4*)&Vt3[jt][jd * 16 + m][g * 4];
                #pragma unroll
                for (int nt = 0; nt < 2; ++nt)
                    O[nt][jd] = mfma16(vf, pv[nt][jt], O[nt][jd]);
            }
    }

    // epilogue: lane holds qrow = l&15, d = jd*16 + 4g + r
    #pragma unroll
    for (int nt = 0; nt < 2; ++nt) {
        float inv = 1.0f / l_s[nt];
        int qrow = qt * 128 + w * 32 + nt * 16 + m;
        #pragma unroll
        for (int jd = 0; jd < 4; ++jd) {
            bf16x4 o;
            #pragma unroll
            for (int r = 0; r < 4; ++r) o[r] = (__bf16)(O[nt][jd][r] * inv);
            *(bf16x4*)(att + ((size_t)b * TT + qrow) * CC + h * HD + jd * 16 + g * 4) = o;
        }
    }
}

// ---------------------------------------------------------------------------
extern "C" void kernel_launch(void* const* d_in, const int* in_sizes, int n_in,
                              void* d_out, int out_size, void* d_ws, size_t ws_size,
                              hipStream_t stream) {
    const float* x   = (const float*)d_in[0];
    const float* Wq  = (const float*)d_in[1];
    const float* Wk  = (const float*)d_in[2];
    const float* Wv  = (const float*)d_in[3];
    const float* Wo  = (const float*)d_in[4];
    const float* bo  = (const float*)d_in[5];
    const float* W1  = (const float*)d_in[6];
    const float* b1  = (const float*)d_in[7];
    const float* W2  = (const float*)d_in[8];
    const float* b2  = (const float*)d_in[9];
    const float* g1  = (const float*)d_in[10];
    const float* be1 = (const float*)d_in[11];
    const float* g2  = (const float*)d_in[12];
    const float* be2 = (const float*)d_in[13];
    float* out = (float*)d_out;

    char* p = (char*)d_ws;
    __bf16* hb    = (__bf16*)p; p += (size_t)BT * CC * 2;        // ln out
    __bf16* qkvb  = (__bf16*)p; p += (size_t)BT * 3072 * 2;      // q|k|(v unused)
    __bf16* vtb   = (__bf16*)p; p += (size_t)BT * CC * 2;        // V^T per head
    __bf16* attb  = (__bf16*)p; p += (size_t)BT * CC * 2;        // attn out
    float*  x2    = (float*)p;  p += (size_t)BT * CC * 4;        // resid 1
    __bf16* ffb   = (__bf16*)p; p += (size_t)BT * 4096 * 2;      // ffn mid
    __bf16* WqkvT = (__bf16*)p; p += (size_t)3072 * 1024 * 2;
    __bf16* WoT   = (__bf16*)p; p += (size_t)1024 * 1024 * 2;
    __bf16* W1T   = (__bf16*)p; p += (size_t)4096 * 1024 * 2;
    __bf16* W2T   = (__bf16*)p; p += (size_t)1024 * 4096 * 2;

    transpose_all<<<12288, 256, 0, stream>>>(Wq, Wk, Wv, Wo, W1, W2,
                                             WqkvT, WoT, W1T, W2T);
    ln_kernel<<<BT, 256, 0, stream>>>(x, g1, be1, hb);
    // fused QKV projection; V written transposed into vtb
    gemm_bf16<128, __bf16, false, false, false, true><<<dim3(24, 32), 256, 0, stream>>>(
        hb, WqkvT, nullptr, nullptr, qkvb, vtb, BT, 3072, 1024);
    attn_mfma2<<<dim3(16, NH, BB), 256, 0, stream>>>(qkvb, vtb, attb);
    // out proj + bias + residual(x) -> x2 (fp32); NT=64 for 512 blocks
    gemm_bf16<64, float, true, false, true, false><<<dim3(16, 32), 256, 0, stream>>>(
        attb, WoT, bo, x, x2, nullptr, BT, 1024, 1024);
    ln_kernel<<<BT, 256, 0, stream>>>(x2, g2, be2, hb);
    // ffn1 + bias + relu -> bf16
    gemm_bf16<128, __bf16, true, true, false, false><<<dim3(32, 32), 256, 0, stream>>>(
        hb, W1T, b1, nullptr, ffb, nullptr, BT, 4096, 1024);
    // ffn2 + bias + residual(x2) -> out (fp32); NT=64 for 512 blocks
    gemm_bf16<64, float, true, false, true, false><<<dim3(16, 32), 256, 0, stream>>>(
        ffb, W2T, b2, x2, out, nullptr, BT, 1024, 4096);
}

// Round 5
// 396.988 us; speedup vs baseline: 11.8489x; 1.0049x over previous
//
#include <hip/hip_runtime.h>
#include <hip/hip_bf16.h>
#include <math.h>

#define BB 2
#define TT 2048
#define CC 1024
#define NH 16
#define HD 64
#define BT (BB*TT)          // 4096 rows
#define LN_EPS 1e-5f
#define ATT_SCALE 0.03125f  // C^-0.5 (reference scales by full C, not head_size)

typedef __bf16 bf16x8 __attribute__((ext_vector_type(8)));
typedef __bf16 bf16x4 __attribute__((ext_vector_type(4)));
typedef short shortx4 __attribute__((ext_vector_type(4)));
typedef float floatx4 __attribute__((ext_vector_type(4)));

__device__ __forceinline__ void gl_lds16(const __bf16* g, __bf16* l) {
    __builtin_amdgcn_global_load_lds((const __attribute__((address_space(1))) void*)g,
                                     (__attribute__((address_space(3))) void*)l,
                                     16, 0, 0);
}

#define MFMA32(a, b, c) __builtin_amdgcn_mfma_f32_16x16x32_bf16(a, b, c, 0, 0, 0)

#if __has_builtin(__builtin_amdgcn_mfma_f32_16x16x16_bf16)
__device__ __forceinline__ floatx4 mfma16(bf16x4 a, bf16x4 b, floatx4 c) {
    return __builtin_amdgcn_mfma_f32_16x16x16_bf16(a, b, c, 0, 0, 0);
}
#else
__device__ __forceinline__ floatx4 mfma16(bf16x4 a, bf16x4 b, floatx4 c) {
    return __builtin_amdgcn_mfma_f32_16x16x16bf16_1k(
        __builtin_bit_cast(shortx4, a), __builtin_bit_cast(shortx4, b), c, 0, 0, 0);
}
#endif

// ---------------------------------------------------------------------------
// LayerNorm: fp32 in -> bf16 out. One block (256 thr) per row.
// ---------------------------------------------------------------------------
__global__ __launch_bounds__(256) void ln_kernel(const float* __restrict__ x,
                                                 const float* __restrict__ g,
                                                 const float* __restrict__ b,
                                                 __bf16* __restrict__ out) {
    int row = blockIdx.x;
    const float4* xr = (const float4*)(x + (size_t)row * CC);
    float4 v = xr[threadIdx.x];
    float s  = v.x + v.y + v.z + v.w;
    float ss = v.x*v.x + v.y*v.y + v.z*v.z + v.w*v.w;
    #pragma unroll
    for (int off = 32; off; off >>= 1) {
        s  += __shfl_down(s, off);
        ss += __shfl_down(ss, off);
    }
    __shared__ float rs_[4], rss_[4];
    __shared__ float mu_s, inv_s;
    int lane = threadIdx.x & 63, wid = threadIdx.x >> 6;
    if (lane == 0) { rs_[wid] = s; rss_[wid] = ss; }
    __syncthreads();
    if (threadIdx.x == 0) {
        float S  = rs_[0] + rs_[1] + rs_[2] + rs_[3];
        float SS = rss_[0] + rss_[1] + rss_[2] + rss_[3];
        float mu  = S * (1.0f / CC);
        float var = SS * (1.0f / CC) - mu * mu;
        mu_s  = mu;
        inv_s = rsqrtf(var + LN_EPS);
    }
    __syncthreads();
    float mu = mu_s, inv = inv_s;
    float4 gv = ((const float4*)g)[threadIdx.x];
    float4 bv = ((const float4*)b)[threadIdx.x];
    bf16x4 o;
    o[0] = (__bf16)((v.x - mu) * inv * gv.x + bv.x);
    o[1] = (__bf16)((v.y - mu) * inv * gv.y + bv.y);
    o[2] = (__bf16)((v.z - mu) * inv * gv.z + bv.z);
    o[3] = (__bf16)((v.w - mu) * inv * gv.w + bv.w);
    *(bf16x4*)(out + (size_t)row * CC + threadIdx.x * 4) = o;
}

// ---------------------------------------------------------------------------
// Reduce 2 bf16 split-K partials + bias + residual -> x2 (fp32), then LN ->
// hb (bf16). Fuses the Wo epilogue with ln2. One block per row.
// ---------------------------------------------------------------------------
__global__ __launch_bounds__(256) void reduce_wo_ln(const __bf16* __restrict__ P,
                                                    const float* __restrict__ bo,
                                                    const float* __restrict__ x,
                                                    const float* __restrict__ g2,
                                                    const float* __restrict__ be2,
                                                    float* __restrict__ x2,
                                                    __bf16* __restrict__ hb) {
    int row = blockIdx.x;
    int c = threadIdx.x * 4;
    bf16x4 a0 = *(const bf16x4*)(P + (size_t)row * CC + c);
    bf16x4 a1 = *(const bf16x4*)(P + (size_t)BT * CC + (size_t)row * CC + c);
    float4 xb = *(const float4*)(x + (size_t)row * CC + c);
    float4 bb = *(const float4*)(bo + c);
    float4 v;
    v.x = xb.x + bb.x + (float)a0[0] + (float)a1[0];
    v.y = xb.y + bb.y + (float)a0[1] + (float)a1[1];
    v.z = xb.z + bb.z + (float)a0[2] + (float)a1[2];
    v.w = xb.w + bb.w + (float)a0[3] + (float)a1[3];
    *(float4*)(x2 + (size_t)row * CC + c) = v;

    float s  = v.x + v.y + v.z + v.w;
    float ss = v.x*v.x + v.y*v.y + v.z*v.z + v.w*v.w;
    #pragma unroll
    for (int off = 32; off; off >>= 1) {
        s  += __shfl_down(s, off);
        ss += __shfl_down(ss, off);
    }
    __shared__ float rs_[4], rss_[4];
    __shared__ float mu_s, inv_s;
    int lane = threadIdx.x & 63, wid = threadIdx.x >> 6;
    if (lane == 0) { rs_[wid] = s; rss_[wid] = ss; }
    __syncthreads();
    if (threadIdx.x == 0) {
        float S  = rs_[0] + rs_[1] + rs_[2] + rs_[3];
        float SS = rss_[0] + rss_[1] + rss_[2] + rss_[3];
        float mu  = S * (1.0f / CC);
        float var = SS * (1.0f / CC) - mu * mu;
        mu_s  = mu;
        inv_s = rsqrtf(var + LN_EPS);
    }
    __syncthreads();
    float mu = mu_s, inv = inv_s;
    float4 gv = ((const float4*)g2)[threadIdx.x];
    float4 bv = ((const float4*)be2)[threadIdx.x];
    bf16x4 o;
    o[0] = (__bf16)((v.x - mu) * inv * gv.x + bv.x);
    o[1] = (__bf16)((v.y - mu) * inv * gv.y + bv.y);
    o[2] = (__bf16)((v.z - mu) * inv * gv.z + bv.z);
    o[3] = (__bf16)((v.w - mu) * inv * gv.w + bv.w);
    *(bf16x4*)(hb + (size_t)row * CC + c) = o;
}

// ---------------------------------------------------------------------------
// Reduce 4 bf16 split-K partials + bias + residual(x2) -> out (fp32).
// ---------------------------------------------------------------------------
__global__ __launch_bounds__(256) void reduce_ffn(const __bf16* __restrict__ P,
                                                  const float* __restrict__ b2,
                                                  const float* __restrict__ x2,
                                                  float* __restrict__ out) {
    int row = blockIdx.x;
    int c = threadIdx.x * 4;
    const size_t S = (size_t)BT * CC;
    float4 v = *(const float4*)(x2 + (size_t)row * CC + c);
    float4 bb = *(const float4*)(b2 + c);
    v.x += bb.x; v.y += bb.y; v.z += bb.z; v.w += bb.w;
    #pragma unroll
    for (int z = 0; z < 4; ++z) {
        bf16x4 a = *(const bf16x4*)(P + z * S + (size_t)row * CC + c);
        v.x += (float)a[0]; v.y += (float)a[1]; v.z += (float)a[2]; v.w += (float)a[3];
    }
    *(float4*)(out + (size_t)row * CC + c) = v;
}

// ---------------------------------------------------------------------------
// All weight transposes fused in one launch. 32x32 tiles; block-uniform branch.
// ---------------------------------------------------------------------------
__global__ __launch_bounds__(256) void transpose_all(
        const float* __restrict__ Wq, const float* __restrict__ Wk,
        const float* __restrict__ Wv, const float* __restrict__ Wo,
        const float* __restrict__ W1, const float* __restrict__ W2,
        __bf16* __restrict__ WqkvT, __bf16* __restrict__ WoT,
        __bf16* __restrict__ W1T, __bf16* __restrict__ W2T) {
    int idx = blockIdx.x;
    const float* src; __bf16* dst; int K, N, tn, tk;
    if (idx < 3072) {                      // Wq|Wk|Wv -> WqkvT (stacked)
        int wsel = idx >> 10, local = idx & 1023;
        src = (wsel == 0) ? Wq : (wsel == 1 ? Wk : Wv);
        dst = WqkvT + (size_t)wsel * 1024 * 1024;
        K = 1024; N = 1024; tn = local & 31; tk = local >> 5;
    } else if (idx < 4096) {
        int local = idx - 3072;
        src = Wo; dst = WoT; K = 1024; N = 1024; tn = local & 31; tk = local >> 5;
    } else if (idx < 8192) {
        int local = idx - 4096;
        src = W1; dst = W1T; K = 1024; N = 4096; tn = local & 127; tk = local >> 7;
    } else {
        int local = idx - 8192;
        src = W2; dst = W2T; K = 4096; N = 1024; tn = local & 31; tk = local >> 5;
    }
    __shared__ float t[32][33];
    int n0 = tn * 32, k0 = tk * 32;
    int tx = threadIdx.x & 31, ty = threadIdx.x >> 5;
    #pragma unroll
    for (int r = ty; r < 32; r += 8)
        t[r][tx] = src[(size_t)(k0 + r) * N + n0 + tx];
    __syncthreads();
    #pragma unroll
    for (int r = ty; r < 32; r += 8)
        dst[(size_t)(n0 + r) * K + k0 + tx] = (__bf16)t[tx][r];
}

// ---------------------------------------------------------------------------
// bf16 MFMA GEMM: C[M,N] = A[M,K] @ Bt[N,K]^T.
// Tile 128 x NT (NT=128 or 64), BK=32, 256 thr. SK>1: split-K, bf16 partials
// written to C + z*M*N (no bias/res). VSPLIT: V columns written transposed.
// ---------------------------------------------------------------------------
template<int NT, int SK, typename OT, bool BIAS, bool RELU, bool RES, bool VSPLIT>
__global__ __launch_bounds__(256) void gemm_bf16(const __bf16* __restrict__ A,
                                                 const __bf16* __restrict__ Bt,
                                                 const float* __restrict__ bias,
                                                 const float* __restrict__ res,
                                                 OT* __restrict__ C,
                                                 __bf16* __restrict__ vt,
                                                 int M, int N, int K) {
    constexpr int JN = NT / 32;
    __shared__ __bf16 As[128 * 32];
    __shared__ __bf16 Bs[NT * 32];
    const int tid = threadIdx.x;
    const int l = tid & 63, w = tid >> 6;
    const int m = l & 15, g = l >> 4;
    const int wm = w >> 1, wn = w & 1;
    const int m0 = blockIdx.y * 128, n0 = blockIdx.x * NT;
    const int Keff = K / SK;
    const int kbase = (SK > 1) ? (int)blockIdx.z * Keff : 0;

    const int srow = w * 16 + (l >> 2);
    const int skof = (l & 3) * 8;
    const __bf16* ga = A  + (size_t)(m0 + srow) * K + kbase + skof;
    const __bf16* gb = Bt + (size_t)(n0 + srow) * K + kbase + skof;
    __bf16* la0 = As + w * 512;
    __bf16* lb0 = Bs + w * 512;

    floatx4 acc[4][JN];
    #pragma unroll
    for (int i = 0; i < 4; ++i)
        #pragma unroll
        for (int j = 0; j < JN; ++j) {
            floatx4 z = {0.f, 0.f, 0.f, 0.f};
            acc[i][j] = z;
        }

    for (int kt = 0; kt < Keff; kt += 32) {
        __syncthreads();
        gl_lds16(ga,                  la0);
        gl_lds16(ga + (size_t)64 * K, la0 + 2048);
        gl_lds16(gb,                  lb0);
        if (NT == 128)
            gl_lds16(gb + (size_t)64 * K, lb0 + 2048);
        ga += 32; gb += 32;
        __syncthreads();

        bf16x8 af[4], bfr[JN];
        #pragma unroll
        for (int i = 0; i < 4; ++i)
            af[i] = *(const bf16x8*)&As[(wm * 64 + i * 16 + m) * 32 + g * 8];
        #pragma unroll
        for (int j = 0; j < JN; ++j)
            bfr[j] = *(const bf16x8*)&Bs[(wn * (NT / 2) + j * 16 + m) * 32 + g * 8];
        #pragma unroll
        for (int i = 0; i < 4; ++i)
            #pragma unroll
            for (int j = 0; j < JN; ++j)
                acc[i][j] = MFMA32(af[i], bfr[j], acc[i][j]);
    }

    if (SK > 1) {
        __bf16* P = (__bf16*)C + (size_t)blockIdx.z * M * N;
        #pragma unroll
        for (int i = 0; i < 4; ++i) {
            int row = m0 + wm * 64 + i * 16 + g * 4;
            #pragma unroll
            for (int j = 0; j < JN; ++j) {
                int col = n0 + wn * (NT / 2) + j * 16 + m;
                #pragma unroll
                for (int r = 0; r < 4; ++r)
                    P[(size_t)(row + r) * N + col] = (__bf16)acc[i][j][r];
            }
        }
    } else if (VSPLIT && n0 >= 2048) {
        // V columns: write transposed per-head into vt [(b*16+h)*64+d][2048]
        #pragma unroll
        for (int i = 0; i < 4; ++i) {
            int row = m0 + wm * 64 + i * 16 + g * 4;
            int bb = row >> 11, t0 = row & 2047;
            #pragma unroll
            for (int j = 0; j < JN; ++j) {
                int cv = n0 + wn * (NT / 2) + j * 16 + m - 2048;
                bf16x4 o;
                #pragma unroll
                for (int r = 0; r < 4; ++r) o[r] = (__bf16)acc[i][j][r];
                *(bf16x4*)(vt + ((size_t)(bb * NH + (cv >> 6)) * HD + (cv & 63)) * 2048 + t0) = o;
            }
        }
    } else {
        #pragma unroll
        for (int i = 0; i < 4; ++i) {
            int row = m0 + wm * 64 + i * 16 + g * 4;
            #pragma unroll
            for (int j = 0; j < JN; ++j) {
                int col = n0 + wn * (NT / 2) + j * 16 + m;
                float bv = BIAS ? bias[col] : 0.0f;
                #pragma unroll
                for (int r = 0; r < 4; ++r) {
                    float vo = acc[i][j][r] + bv;
                    if (RELU) vo = fmaxf(vo, 0.0f);
                    if (RES)  vo += res[(size_t)(row + r) * N + col];
                    C[(size_t)(row + r) * N + col] = (OT)vo;
                }
            }
        }
    }
}

// ---------------------------------------------------------------------------
// Flash attention, S^T orientation (see round-4 notes). One block per
// (b, h, 128-q-tile); 4 waves x 32 q-rows. P stays in registers (B-layout).
// ---------------------------------------------------------------------------
__global__ __launch_bounds__(256, 2) void attn_mfma2(const __bf16* __restrict__ qkv,
                                                     const __bf16* __restrict__ vt,
                                                     __bf16* __restrict__ att) {
    const int qt = 15 - (int)blockIdx.x;   // heavy tiles first
    const int h = blockIdx.y, b = blockIdx.z;
    const int tid = threadIdx.x;
    const int l = tid & 63, w = tid >> 6;
    const int m = l & 15, g = l >> 4;

    __shared__ __bf16 Ks[2][128][32];   // [d-half][key][32 d]   16 KB
    __shared__ __bf16 Vt3[8][64][16];   // [key/16][d][16 keys]  16 KB

    const __bf16* qp = qkv + (size_t)b * TT * 3072 + h * HD;
    const __bf16* kp = qp + 1024;
    const __bf16* vh = vt + (size_t)(b * NH + h) * HD * 2048;

    bf16x8 qb[2][2];
    #pragma unroll
    for (int nt = 0; nt < 2; ++nt) {
        int qrow = qt * 128 + w * 32 + nt * 16 + m;
        qb[nt][0] = *(const bf16x8*)(qp + (size_t)qrow * 3072 + g * 8);
        qb[nt][1] = *(const bf16x8*)(qp + (size_t)qrow * 3072 + 32 + g * 8);
    }

    floatx4 O[2][4];
    float m_s[2], l_s[2];
    #pragma unroll
    for (int nt = 0; nt < 2; ++nt) {
        #pragma unroll
        for (int jd = 0; jd < 4; ++jd) {
            floatx4 z = {0.f, 0.f, 0.f, 0.f};
            O[nt][jd] = z;
        }
        m_s[nt] = -1e30f; l_s[nt] = 0.0f;
    }

    for (int kt = 0; kt <= qt; ++kt) {
        __syncthreads();
        #pragma unroll
        for (int c = 0; c < 4; ++c) {
            int idx = w * 4 + c;
            int dh = idx >> 3, k16 = idx & 7;
            gl_lds16(kp + (size_t)(kt * 128 + k16 * 16 + (l >> 2)) * 3072 + dh * 32 + (l & 3) * 8,
                     (__bf16*)Ks + dh * 4096 + k16 * 512);
        }
        #pragma unroll
        for (int c = 0; c < 4; ++c) {
            int idx = w * 4 + c;
            int jt = idx >> 1, dhf = idx & 1;
            gl_lds16(vh + (size_t)(dhf * 32 + (l >> 1)) * 2048 + kt * 128 + jt * 16 + (l & 1) * 8,
                     (__bf16*)Vt3 + jt * 1024 + dhf * 512);
        }
        __syncthreads();

        floatx4 S[2][8];
        #pragma unroll
        for (int jt = 0; jt < 8; ++jt) {
            bf16x8 kf0 = *(const bf16x8*)&Ks[0][jt * 16 + m][g * 8];
            bf16x8 kf1 = *(const bf16x8*)&Ks[1][jt * 16 + m][g * 8];
            #pragma unroll
            for (int nt = 0; nt < 2; ++nt) {
                floatx4 z = {0.f, 0.f, 0.f, 0.f};
                z = MFMA32(kf0, qb[nt][0], z);
                S[nt][jt] = MFMA32(kf1, qb[nt][1], z);
            }
        }

        bf16x4 pv[2][8];
        const bool last = (kt == qt);
        #pragma unroll
        for (int nt = 0; nt < 2; ++nt) {
            if (last) {
                int qr = w * 32 + nt * 16 + m;
                #pragma unroll
                for (int jt = 0; jt < 8; ++jt)
                    #pragma unroll
                    for (int r = 0; r < 4; ++r)
                        if (jt * 16 + g * 4 + r > qr) S[nt][jt][r] = -1e30f;
            }
            float mx = -1e30f;
            #pragma unroll
            for (int jt = 0; jt < 8; ++jt)
                #pragma unroll
                for (int r = 0; r < 4; ++r)
                    mx = fmaxf(mx, S[nt][jt][r]);
            mx = fmaxf(mx, __shfl_xor(mx, 16, 64));
            mx = fmaxf(mx, __shfl_xor(mx, 32, 64));
            float mnew = fmaxf(m_s[nt], mx);
            float alpha = __expf((m_s[nt] - mnew) * ATT_SCALE);
            m_s[nt] = mnew;
            float mc = mnew * ATT_SCALE;
            float ls = 0.0f;
            #pragma unroll
            for (int jt = 0; jt < 8; ++jt) {
                bf16x4 t;
                #pragma unroll
                for (int r = 0; r < 4; ++r) {
                    float p = __expf(fmaf(S[nt][jt][r], ATT_SCALE, -mc));
                    ls += p;
                    t[r] = (__bf16)p;
                }
                pv[nt][jt] = t;
            }
            ls += __shfl_xor(ls, 16, 64);
            ls += __shfl_xor(ls, 32, 64);
            l_s[nt] = l_s[nt] * alpha + ls;
            #pragma unroll
            for (int jd = 0; jd < 4; ++jd) O[nt][jd] *= alpha;
        }

        #pragma unroll
        for (int jt = 0; jt < 8; ++jt)
            #pragma unroll
            for (int jd = 0; jd < 4; ++jd) {
                bf16x4 vf = *(const bf16x4*)&Vt3[jt][jd * 16 + m][g * 4];
                #pragma unroll
                for (int nt = 0; nt < 2; ++nt)
                    O[nt][jd] = mfma16(vf, pv[nt][jt], O[nt][jd]);
            }
    }

    #pragma unroll
    for (int nt = 0; nt < 2; ++nt) {
        float inv = 1.0f / l_s[nt];
        int qrow = qt * 128 + w * 32 + nt * 16 + m;
        #pragma unroll
        for (int jd = 0; jd < 4; ++jd) {
            bf16x4 o;
            #pragma unroll
            for (int r = 0; r < 4; ++r) o[r] = (__bf16)(O[nt][jd][r] * inv);
            *(bf16x4*)(att + ((size_t)b * TT + qrow) * CC + h * HD + jd * 16 + g * 4) = o;
        }
    }
}

// ---------------------------------------------------------------------------
extern "C" void kernel_launch(void* const* d_in, const int* in_sizes, int n_in,
                              void* d_out, int out_size, void* d_ws, size_t ws_size,
                              hipStream_t stream) {
    const float* x   = (const float*)d_in[0];
    const float* Wq  = (const float*)d_in[1];
    const float* Wk  = (const float*)d_in[2];
    const float* Wv  = (const float*)d_in[3];
    const float* Wo  = (const float*)d_in[4];
    const float* bo  = (const float*)d_in[5];
    const float* W1  = (const float*)d_in[6];
    const float* b1  = (const float*)d_in[7];
    const float* W2  = (const float*)d_in[8];
    const float* b2  = (const float*)d_in[9];
    const float* g1  = (const float*)d_in[10];
    const float* be1 = (const float*)d_in[11];
    const float* g2  = (const float*)d_in[12];
    const float* be2 = (const float*)d_in[13];
    float* out = (float*)d_out;

    char* p = (char*)d_ws;
    // pool32 (32 MB): qkvb(24)+vtb(8) during attention; later Wo partials (16)
    // then FFN2 partials (32) — lifetimes are disjoint.
    char*   pool  = p;          p += (size_t)32 * 1024 * 1024;
    __bf16* qkvb  = (__bf16*)pool;
    __bf16* vtb   = (__bf16*)(pool + (size_t)BT * 3072 * 2);
    __bf16* wop   = (__bf16*)pool;     // 2 x [BT][CC] bf16 partials
    __bf16* ffp   = (__bf16*)pool;     // 4 x [BT][CC] bf16 partials
    __bf16* attb  = (__bf16*)p; p += (size_t)BT * CC * 2;
    __bf16* hb    = (__bf16*)p; p += (size_t)BT * CC * 2;
    float*  x2    = (float*)p;  p += (size_t)BT * CC * 4;
    __bf16* ffb   = (__bf16*)p; p += (size_t)BT * 4096 * 2;
    __bf16* WqkvT = (__bf16*)p; p += (size_t)3072 * 1024 * 2;
    __bf16* WoT   = (__bf16*)p; p += (size_t)1024 * 1024 * 2;
    __bf16* W1T   = (__bf16*)p; p += (size_t)4096 * 1024 * 2;
    __bf16* W2T   = (__bf16*)p; p += (size_t)1024 * 4096 * 2;

    transpose_all<<<12288, 256, 0, stream>>>(Wq, Wk, Wv, Wo, W1, W2,
                                             WqkvT, WoT, W1T, W2T);
    ln_kernel<<<BT, 256, 0, stream>>>(x, g1, be1, hb);
    // fused QKV projection; V written transposed into vtb
    gemm_bf16<128, 1, __bf16, false, false, false, true><<<dim3(24, 32), 256, 0, stream>>>(
        hb, WqkvT, nullptr, nullptr, qkvb, vtb, BT, 3072, 1024);
    attn_mfma2<<<dim3(16, NH, BB), 256, 0, stream>>>(qkvb, vtb, attb);
    // out proj: split-K=2 bf16 partials (overwrites dead qkv pool)
    gemm_bf16<64, 2, __bf16, false, false, false, false><<<dim3(16, 32, 2), 256, 0, stream>>>(
        attb, WoT, nullptr, nullptr, wop, nullptr, BT, 1024, 1024);
    // reduce partials + bo + residual(x) -> x2, fused ln2 -> hb
    reduce_wo_ln<<<BT, 256, 0, stream>>>(wop, bo, x, g2, be2, x2, hb);
    // ffn1 + bias + relu -> bf16
    gemm_bf16<128, 1, __bf16, true, true, false, false><<<dim3(32, 32), 256, 0, stream>>>(
        hb, W1T, b1, nullptr, ffb, nullptr, BT, 4096, 1024);
    // ffn2: split-K=4 bf16 partials (pool free again)
    gemm_bf16<128, 4, __bf16, false, false, false, false><<<dim3(8, 32, 4), 256, 0, stream>>>(
        ffb, W2T, nullptr, nullptr, ffp, nullptr, BT, 1024, 4096);
    // reduce partials + b2 + residual(x2) -> out
    reduce_ffn<<<BT, 256, 0, stream>>>(ffp, b2, x2, out);
}

// Round 6
// 388.600 us; speedup vs baseline: 12.1046x; 1.0216x over previous
//
#include <hip/hip_runtime.h>
#include <hip/hip_bf16.h>
#include <math.h>

#define BB 2
#define TT 2048
#define CC 1024
#define NH 16
#define HD 64
#define BT (BB*TT)          // 4096 rows
#define LN_EPS 1e-5f
#define ATT_SCALE 0.03125f  // C^-0.5 (reference scales by full C, not head_size)

typedef __bf16 bf16x8 __attribute__((ext_vector_type(8)));
typedef __bf16 bf16x4 __attribute__((ext_vector_type(4)));
typedef short shortx4 __attribute__((ext_vector_type(4)));
typedef float floatx4 __attribute__((ext_vector_type(4)));

__device__ __forceinline__ void gl_lds16(const __bf16* g, __bf16* l) {
    __builtin_amdgcn_global_load_lds((const __attribute__((address_space(1))) void*)g,
                                     (__attribute__((address_space(3))) void*)l,
                                     16, 0, 0);
}

#define MFMA32(a, b, c) __builtin_amdgcn_mfma_f32_16x16x32_bf16(a, b, c, 0, 0, 0)

#if __has_builtin(__builtin_amdgcn_mfma_f32_16x16x16_bf16)
__device__ __forceinline__ floatx4 mfma16(bf16x4 a, bf16x4 b, floatx4 c) {
    return __builtin_amdgcn_mfma_f32_16x16x16_bf16(a, b, c, 0, 0, 0);
}
#else
__device__ __forceinline__ floatx4 mfma16(bf16x4 a, bf16x4 b, floatx4 c) {
    return __builtin_amdgcn_mfma_f32_16x16x16bf16_1k(
        __builtin_bit_cast(shortx4, a), __builtin_bit_cast(shortx4, b), c, 0, 0, 0);
}
#endif

// XCD-aware block remap: blocks with lin%8==c (dispatched to XCD c under
// round-robin) get a CONTIGUOUS chunk of the (x,y,z) lex order, so each
// A-tile (shared across x) is fetched by exactly one XCD; cross-XCD B
// re-reads hit the 256MB L3. Requires total blocks % 8 == 0.
__device__ __forceinline__ void swizzle_xcd(int& xb, int& yb, int& zb) {
    int nx = gridDim.x, ny = gridDim.y;
    int total = nx * ny * (int)gridDim.z;
    int lin = blockIdx.x + nx * (blockIdx.y + ny * blockIdx.z);
    int c = lin & 7, s = lin >> 3;
    int idx = c * (total >> 3) + s;
    xb = idx % nx;
    yb = (idx / nx) % ny;
    zb = idx / (nx * ny);
}

// ---------------------------------------------------------------------------
// LayerNorm: fp32 in -> bf16 out. One block (256 thr) per row.
// ---------------------------------------------------------------------------
__global__ __launch_bounds__(256) void ln_kernel(const float* __restrict__ x,
                                                 const float* __restrict__ g,
                                                 const float* __restrict__ b,
                                                 __bf16* __restrict__ out) {
    int row = blockIdx.x;
    const float4* xr = (const float4*)(x + (size_t)row * CC);
    float4 v = xr[threadIdx.x];
    float s  = v.x + v.y + v.z + v.w;
    float ss = v.x*v.x + v.y*v.y + v.z*v.z + v.w*v.w;
    #pragma unroll
    for (int off = 32; off; off >>= 1) {
        s  += __shfl_down(s, off);
        ss += __shfl_down(ss, off);
    }
    __shared__ float rs_[4], rss_[4];
    __shared__ float mu_s, inv_s;
    int lane = threadIdx.x & 63, wid = threadIdx.x >> 6;
    if (lane == 0) { rs_[wid] = s; rss_[wid] = ss; }
    __syncthreads();
    if (threadIdx.x == 0) {
        float S  = rs_[0] + rs_[1] + rs_[2] + rs_[3];
        float SS = rss_[0] + rss_[1] + rss_[2] + rss_[3];
        float mu  = S * (1.0f / CC);
        float var = SS * (1.0f / CC) - mu * mu;
        mu_s  = mu;
        inv_s = rsqrtf(var + LN_EPS);
    }
    __syncthreads();
    float mu = mu_s, inv = inv_s;
    float4 gv = ((const float4*)g)[threadIdx.x];
    float4 bv = ((const float4*)b)[threadIdx.x];
    bf16x4 o;
    o[0] = (__bf16)((v.x - mu) * inv * gv.x + bv.x);
    o[1] = (__bf16)((v.y - mu) * inv * gv.y + bv.y);
    o[2] = (__bf16)((v.z - mu) * inv * gv.z + bv.z);
    o[3] = (__bf16)((v.w - mu) * inv * gv.w + bv.w);
    *(bf16x4*)(out + (size_t)row * CC + threadIdx.x * 4) = o;
}

// ---------------------------------------------------------------------------
// Reduce 2 bf16 split-K partials + bias + residual -> x2 (fp32), then LN ->
// hb (bf16). Fuses the Wo epilogue with ln2. One block per row.
// ---------------------------------------------------------------------------
__global__ __launch_bounds__(256) void reduce_wo_ln(const __bf16* __restrict__ P,
                                                    const float* __restrict__ bo,
                                                    const float* __restrict__ x,
                                                    const float* __restrict__ g2,
                                                    const float* __restrict__ be2,
                                                    float* __restrict__ x2,
                                                    __bf16* __restrict__ hb) {
    int row = blockIdx.x;
    int c = threadIdx.x * 4;
    bf16x4 a0 = *(const bf16x4*)(P + (size_t)row * CC + c);
    bf16x4 a1 = *(const bf16x4*)(P + (size_t)BT * CC + (size_t)row * CC + c);
    float4 xb = *(const float4*)(x + (size_t)row * CC + c);
    float4 bb = *(const float4*)(bo + c);
    float4 v;
    v.x = xb.x + bb.x + (float)a0[0] + (float)a1[0];
    v.y = xb.y + bb.y + (float)a0[1] + (float)a1[1];
    v.z = xb.z + bb.z + (float)a0[2] + (float)a1[2];
    v.w = xb.w + bb.w + (float)a0[3] + (float)a1[3];
    *(float4*)(x2 + (size_t)row * CC + c) = v;

    float s  = v.x + v.y + v.z + v.w;
    float ss = v.x*v.x + v.y*v.y + v.z*v.z + v.w*v.w;
    #pragma unroll
    for (int off = 32; off; off >>= 1) {
        s  += __shfl_down(s, off);
        ss += __shfl_down(ss, off);
    }
    __shared__ float rs_[4], rss_[4];
    __shared__ float mu_s, inv_s;
    int lane = threadIdx.x & 63, wid = threadIdx.x >> 6;
    if (lane == 0) { rs_[wid] = s; rss_[wid] = ss; }
    __syncthreads();
    if (threadIdx.x == 0) {
        float S  = rs_[0] + rs_[1] + rs_[2] + rs_[3];
        float SS = rss_[0] + rss_[1] + rss_[2] + rss_[3];
        float mu  = S * (1.0f / CC);
        float var = SS * (1.0f / CC) - mu * mu;
        mu_s  = mu;
        inv_s = rsqrtf(var + LN_EPS);
    }
    __syncthreads();
    float mu = mu_s, inv = inv_s;
    float4 gv = ((const float4*)g2)[threadIdx.x];
    float4 bv = ((const float4*)be2)[threadIdx.x];
    bf16x4 o;
    o[0] = (__bf16)((v.x - mu) * inv * gv.x + bv.x);
    o[1] = (__bf16)((v.y - mu) * inv * gv.y + bv.y);
    o[2] = (__bf16)((v.z - mu) * inv * gv.z + bv.z);
    o[3] = (__bf16)((v.w - mu) * inv * gv.w + bv.w);
    *(bf16x4*)(hb + (size_t)row * CC + c) = o;
}

// ---------------------------------------------------------------------------
// Reduce 4 bf16 split-K partials + bias + residual(x2) -> out (fp32).
// ---------------------------------------------------------------------------
__global__ __launch_bounds__(256) void reduce_ffn(const __bf16* __restrict__ P,
                                                  const float* __restrict__ b2,
                                                  const float* __restrict__ x2,
                                                  float* __restrict__ out) {
    int row = blockIdx.x;
    int c = threadIdx.x * 4;
    const size_t S = (size_t)BT * CC;
    float4 v = *(const float4*)(x2 + (size_t)row * CC + c);
    float4 bb = *(const float4*)(b2 + c);
    v.x += bb.x; v.y += bb.y; v.z += bb.z; v.w += bb.w;
    #pragma unroll
    for (int z = 0; z < 4; ++z) {
        bf16x4 a = *(const bf16x4*)(P + z * S + (size_t)row * CC + c);
        v.x += (float)a[0]; v.y += (float)a[1]; v.z += (float)a[2]; v.w += (float)a[3];
    }
    *(float4*)(out + (size_t)row * CC + c) = v;
}

// ---------------------------------------------------------------------------
// All weight transposes fused in one launch. 32x32 tiles; block-uniform branch.
// ---------------------------------------------------------------------------
__global__ __launch_bounds__(256) void transpose_all(
        const float* __restrict__ Wq, const float* __restrict__ Wk,
        const float* __restrict__ Wv, const float* __restrict__ Wo,
        const float* __restrict__ W1, const float* __restrict__ W2,
        __bf16* __restrict__ WqkvT, __bf16* __restrict__ WoT,
        __bf16* __restrict__ W1T, __bf16* __restrict__ W2T) {
    int idx = blockIdx.x;
    const float* src; __bf16* dst; int K, N, tn, tk;
    if (idx < 3072) {                      // Wq|Wk|Wv -> WqkvT (stacked)
        int wsel = idx >> 10, local = idx & 1023;
        src = (wsel == 0) ? Wq : (wsel == 1 ? Wk : Wv);
        dst = WqkvT + (size_t)wsel * 1024 * 1024;
        K = 1024; N = 1024; tn = local & 31; tk = local >> 5;
    } else if (idx < 4096) {
        int local = idx - 3072;
        src = Wo; dst = WoT; K = 1024; N = 1024; tn = local & 31; tk = local >> 5;
    } else if (idx < 8192) {
        int local = idx - 4096;
        src = W1; dst = W1T; K = 1024; N = 4096; tn = local & 127; tk = local >> 7;
    } else {
        int local = idx - 8192;
        src = W2; dst = W2T; K = 4096; N = 1024; tn = local & 31; tk = local >> 5;
    }
    __shared__ float t[32][33];
    int n0 = tn * 32, k0 = tk * 32;
    int tx = threadIdx.x & 31, ty = threadIdx.x >> 5;
    #pragma unroll
    for (int r = ty; r < 32; r += 8)
        t[r][tx] = src[(size_t)(k0 + r) * N + n0 + tx];
    __syncthreads();
    #pragma unroll
    for (int r = ty; r < 32; r += 8)
        dst[(size_t)(n0 + r) * K + k0 + tx] = (__bf16)t[tx][r];
}

// ---------------------------------------------------------------------------
// bf16 MFMA GEMM: C[M,N] = A[M,K] @ Bt[N,K]^T.
// Tile 128 x NT (NT=128 or 64), BK=32, 256 thr. SK>1: split-K, bf16 partials
// written to C + z*M*N (no bias/res). VSPLIT: V columns written transposed.
// XCD-swizzled block mapping (see swizzle_xcd).
// ---------------------------------------------------------------------------
template<int NT, int SK, typename OT, bool BIAS, bool RELU, bool RES, bool VSPLIT>
__global__ __launch_bounds__(256) void gemm_bf16(const __bf16* __restrict__ A,
                                                 const __bf16* __restrict__ Bt,
                                                 const float* __restrict__ bias,
                                                 const float* __restrict__ res,
                                                 OT* __restrict__ C,
                                                 __bf16* __restrict__ vt,
                                                 int M, int N, int K) {
    constexpr int JN = NT / 32;
    __shared__ __bf16 As[128 * 32];
    __shared__ __bf16 Bs[NT * 32];
    int bx, by, bz;
    swizzle_xcd(bx, by, bz);
    const int tid = threadIdx.x;
    const int l = tid & 63, w = tid >> 6;
    const int m = l & 15, g = l >> 4;
    const int wm = w >> 1, wn = w & 1;
    const int m0 = by * 128, n0 = bx * NT;
    const int Keff = K / SK;
    const int kbase = (SK > 1) ? bz * Keff : 0;

    const int srow = w * 16 + (l >> 2);
    const int skof = (l & 3) * 8;
    const __bf16* ga = A  + (size_t)(m0 + srow) * K + kbase + skof;
    const __bf16* gb = Bt + (size_t)(n0 + srow) * K + kbase + skof;
    __bf16* la0 = As + w * 512;
    __bf16* lb0 = Bs + w * 512;

    floatx4 acc[4][JN];
    #pragma unroll
    for (int i = 0; i < 4; ++i)
        #pragma unroll
        for (int j = 0; j < JN; ++j) {
            floatx4 z = {0.f, 0.f, 0.f, 0.f};
            acc[i][j] = z;
        }

    for (int kt = 0; kt < Keff; kt += 32) {
        __syncthreads();
        gl_lds16(ga,                  la0);
        gl_lds16(ga + (size_t)64 * K, la0 + 2048);
        gl_lds16(gb,                  lb0);
        if (NT == 128)
            gl_lds16(gb + (size_t)64 * K, lb0 + 2048);
        ga += 32; gb += 32;
        __syncthreads();

        bf16x8 af[4], bfr[JN];
        #pragma unroll
        for (int i = 0; i < 4; ++i)
            af[i] = *(const bf16x8*)&As[(wm * 64 + i * 16 + m) * 32 + g * 8];
        #pragma unroll
        for (int j = 0; j < JN; ++j)
            bfr[j] = *(const bf16x8*)&Bs[(wn * (NT / 2) + j * 16 + m) * 32 + g * 8];
        #pragma unroll
        for (int i = 0; i < 4; ++i)
            #pragma unroll
            for (int j = 0; j < JN; ++j)
                acc[i][j] = MFMA32(af[i], bfr[j], acc[i][j]);
    }

    if (SK > 1) {
        __bf16* P = (__bf16*)C + (size_t)bz * M * N;
        #pragma unroll
        for (int i = 0; i < 4; ++i) {
            int row = m0 + wm * 64 + i * 16 + g * 4;
            #pragma unroll
            for (int j = 0; j < JN; ++j) {
                int col = n0 + wn * (NT / 2) + j * 16 + m;
                #pragma unroll
                for (int r = 0; r < 4; ++r)
                    P[(size_t)(row + r) * N + col] = (__bf16)acc[i][j][r];
            }
        }
    } else if (VSPLIT && n0 >= 2048) {
        // V columns: write transposed per-head into vt [(b*16+h)*64+d][2048]
        #pragma unroll
        for (int i = 0; i < 4; ++i) {
            int row = m0 + wm * 64 + i * 16 + g * 4;
            int bb = row >> 11, t0 = row & 2047;
            #pragma unroll
            for (int j = 0; j < JN; ++j) {
                int cv = n0 + wn * (NT / 2) + j * 16 + m - 2048;
                bf16x4 o;
                #pragma unroll
                for (int r = 0; r < 4; ++r) o[r] = (__bf16)acc[i][j][r];
                *(bf16x4*)(vt + ((size_t)(bb * NH + (cv >> 6)) * HD + (cv & 63)) * 2048 + t0) = o;
            }
        }
    } else {
        #pragma unroll
        for (int i = 0; i < 4; ++i) {
            int row = m0 + wm * 64 + i * 16 + g * 4;
            #pragma unroll
            for (int j = 0; j < JN; ++j) {
                int col = n0 + wn * (NT / 2) + j * 16 + m;
                float bv = BIAS ? bias[col] : 0.0f;
                #pragma unroll
                for (int r = 0; r < 4; ++r) {
                    float vo = acc[i][j][r] + bv;
                    if (RELU) vo = fmaxf(vo, 0.0f);
                    if (RES)  vo += res[(size_t)(row + r) * N + col];
                    C[(size_t)(row + r) * N + col] = (OT)vo;
                }
            }
        }
    }
}

// ---------------------------------------------------------------------------
// Flash attention, S^T orientation (see round-4 notes). One block per
// (b, h, 128-q-tile); 4 waves x 32 q-rows. P stays in registers (B-layout).
// ---------------------------------------------------------------------------
__global__ __launch_bounds__(256, 2) void attn_mfma2(const __bf16* __restrict__ qkv,
                                                     const __bf16* __restrict__ vt,
                                                     __bf16* __restrict__ att) {
    const int qt = 15 - (int)blockIdx.x;   // heavy tiles first
    const int h = blockIdx.y, b = blockIdx.z;
    const int tid = threadIdx.x;
    const int l = tid & 63, w = tid >> 6;
    const int m = l & 15, g = l >> 4;

    __shared__ __bf16 Ks[2][128][32];   // [d-half][key][32 d]   16 KB
    __shared__ __bf16 Vt3[8][64][16];   // [key/16][d][16 keys]  16 KB

    const __bf16* qp = qkv + (size_t)b * TT * 3072 + h * HD;
    const __bf16* kp = qp + 1024;
    const __bf16* vh = vt + (size_t)(b * NH + h) * HD * 2048;

    bf16x8 qb[2][2];
    #pragma unroll
    for (int nt = 0; nt < 2; ++nt) {
        int qrow = qt * 128 + w * 32 + nt * 16 + m;
        qb[nt][0] = *(const bf16x8*)(qp + (size_t)qrow * 3072 + g * 8);
        qb[nt][1] = *(const bf16x8*)(qp + (size_t)qrow * 3072 + 32 + g * 8);
    }

    floatx4 O[2][4];
    float m_s[2], l_s[2];
    #pragma unroll
    for (int nt = 0; nt < 2; ++nt) {
        #pragma unroll
        for (int jd = 0; jd < 4; ++jd) {
            floatx4 z = {0.f, 0.f, 0.f, 0.f};
            O[nt][jd] = z;
        }
        m_s[nt] = -1e30f; l_s[nt] = 0.0f;
    }

    for (int kt = 0; kt <= qt; ++kt) {
        __syncthreads();
        #pragma unroll
        for (int c = 0; c < 4; ++c) {
            int idx = w * 4 + c;
            int dh = idx >> 3, k16 = idx & 7;
            gl_lds16(kp + (size_t)(kt * 128 + k16 * 16 + (l >> 2)) * 3072 + dh * 32 + (l & 3) * 8,
                     (__bf16*)Ks + dh * 4096 + k16 * 512);
        }
        #pragma unroll
        for (int c = 0; c < 4; ++c) {
            int idx = w * 4 + c;
            int jt = idx >> 1, dhf = idx & 1;
            gl_lds16(vh + (size_t)(dhf * 32 + (l >> 1)) * 2048 + kt * 128 + jt * 16 + (l & 1) * 8,
                     (__bf16*)Vt3 + jt * 1024 + dhf * 512);
        }
        __syncthreads();

        floatx4 S[2][8];
        #pragma unroll
        for (int jt = 0; jt < 8; ++jt) {
            bf16x8 kf0 = *(const bf16x8*)&Ks[0][jt * 16 + m][g * 8];
            bf16x8 kf1 = *(const bf16x8*)&Ks[1][jt * 16 + m][g * 8];
            #pragma unroll
            for (int nt = 0; nt < 2; ++nt) {
                floatx4 z = {0.f, 0.f, 0.f, 0.f};
                z = MFMA32(kf0, qb[nt][0], z);
                S[nt][jt] = MFMA32(kf1, qb[nt][1], z);
            }
        }

        bf16x4 pv[2][8];
        const bool last = (kt == qt);
        #pragma unroll
        for (int nt = 0; nt < 2; ++nt) {
            if (last) {
                int qr = w * 32 + nt * 16 + m;
                #pragma unroll
                for (int jt = 0; jt < 8; ++jt)
                    #pragma unroll
                    for (int r = 0; r < 4; ++r)
                        if (jt * 16 + g * 4 + r > qr) S[nt][jt][r] = -1e30f;
            }
            float mx = -1e30f;
            #pragma unroll
            for (int jt = 0; jt < 8; ++jt)
                #pragma unroll
                for (int r = 0; r < 4; ++r)
                    mx = fmaxf(mx, S[nt][jt][r]);
            mx = fmaxf(mx, __shfl_xor(mx, 16, 64));
            mx = fmaxf(mx, __shfl_xor(mx, 32, 64));
            float mnew = fmaxf(m_s[nt], mx);
            float alpha = __expf((m_s[nt] - mnew) * ATT_SCALE);
            m_s[nt] = mnew;
            float mc = mnew * ATT_SCALE;
            float ls = 0.0f;
            #pragma unroll
            for (int jt = 0; jt < 8; ++jt) {
                bf16x4 t;
                #pragma unroll
                for (int r = 0; r < 4; ++r) {
                    float p = __expf(fmaf(S[nt][jt][r], ATT_SCALE, -mc));
                    ls += p;
                    t[r] = (__bf16)p;
                }
                pv[nt][jt] = t;
            }
            ls += __shfl_xor(ls, 16, 64);
            ls += __shfl_xor(ls, 32, 64);
            l_s[nt] = l_s[nt] * alpha + ls;
            #pragma unroll
            for (int jd = 0; jd < 4; ++jd) O[nt][jd] *= alpha;
        }

        #pragma unroll
        for (int jt = 0; jt < 8; ++jt)
            #pragma unroll
            for (int jd = 0; jd < 4; ++jd) {
                bf16x4 vf = *(const bf16x4*)&Vt3[jt][jd * 16 + m][g * 4];
                #pragma unroll
                for (int nt = 0; nt < 2; ++nt)
                    O[nt][jd] = mfma16(vf, pv[nt][jt], O[nt][jd]);
            }
    }

    #pragma unroll
    for (int nt = 0; nt < 2; ++nt) {
        float inv = 1.0f / l_s[nt];
        int qrow = qt * 128 + w * 32 + nt * 16 + m;
        #pragma unroll
        for (int jd = 0; jd < 4; ++jd) {
            bf16x4 o;
            #pragma unroll
            for (int r = 0; r < 4; ++r) o[r] = (__bf16)(O[nt][jd][r] * inv);
            *(bf16x4*)(att + ((size_t)b * TT + qrow) * CC + h * HD + jd * 16 + g * 4) = o;
        }
    }
}

// ---------------------------------------------------------------------------
extern "C" void kernel_launch(void* const* d_in, const int* in_sizes, int n_in,
                              void* d_out, int out_size, void* d_ws, size_t ws_size,
                              hipStream_t stream) {
    const float* x   = (const float*)d_in[0];
    const float* Wq  = (const float*)d_in[1];
    const float* Wk  = (const float*)d_in[2];
    const float* Wv  = (const float*)d_in[3];
    const float* Wo  = (const float*)d_in[4];
    const float* bo  = (const float*)d_in[5];
    const float* W1  = (const float*)d_in[6];
    const float* b1  = (const float*)d_in[7];
    const float* W2  = (const float*)d_in[8];
    const float* b2  = (const float*)d_in[9];
    const float* g1  = (const float*)d_in[10];
    const float* be1 = (const float*)d_in[11];
    const float* g2  = (const float*)d_in[12];
    const float* be2 = (const float*)d_in[13];
    float* out = (float*)d_out;

    char* p = (char*)d_ws;
    // pool32 (32 MB): qkvb(24)+vtb(8) during attention; later Wo partials (16)
    // then FFN2 partials (32) — lifetimes are disjoint.
    char*   pool  = p;          p += (size_t)32 * 1024 * 1024;
    __bf16* qkvb  = (__bf16*)pool;
    __bf16* vtb   = (__bf16*)(pool + (size_t)BT * 3072 * 2);
    __bf16* wop   = (__bf16*)pool;     // 2 x [BT][CC] bf16 partials
    __bf16* ffp   = (__bf16*)pool;     // 4 x [BT][CC] bf16 partials
    __bf16* attb  = (__bf16*)p; p += (size_t)BT * CC * 2;
    __bf16* hb    = (__bf16*)p; p += (size_t)BT * CC * 2;
    float*  x2    = (float*)p;  p += (size_t)BT * CC * 4;
    __bf16* ffb   = (__bf16*)p; p += (size_t)BT * 4096 * 2;
    __bf16* WqkvT = (__bf16*)p; p += (size_t)3072 * 1024 * 2;
    __bf16* WoT   = (__bf16*)p; p += (size_t)1024 * 1024 * 2;
    __bf16* W1T   = (__bf16*)p; p += (size_t)4096 * 1024 * 2;
    __bf16* W2T   = (__bf16*)p; p += (size_t)1024 * 4096 * 2;

    transpose_all<<<12288, 256, 0, stream>>>(Wq, Wk, Wv, Wo, W1, W2,
                                             WqkvT, WoT, W1T, W2T);
    ln_kernel<<<BT, 256, 0, stream>>>(x, g1, be1, hb);
    // fused QKV projection; V written transposed into vtb
    gemm_bf16<128, 1, __bf16, false, false, false, true><<<dim3(24, 32), 256, 0, stream>>>(
        hb, WqkvT, nullptr, nullptr, qkvb, vtb, BT, 3072, 1024);
    attn_mfma2<<<dim3(16, NH, BB), 256, 0, stream>>>(qkvb, vtb, attb);
    // out proj: split-K=2 bf16 partials (overwrites dead qkv pool)
    gemm_bf16<64, 2, __bf16, false, false, false, false><<<dim3(16, 32, 2), 256, 0, stream>>>(
        attb, WoT, nullptr, nullptr, wop, nullptr, BT, 1024, 1024);
    // reduce partials + bo + residual(x) -> x2, fused ln2 -> hb
    reduce_wo_ln<<<BT, 256, 0, stream>>>(wop, bo, x, g2, be2, x2, hb);
    // ffn1 + bias + relu -> bf16
    gemm_bf16<128, 1, __bf16, true, true, false, false><<<dim3(32, 32), 256, 0, stream>>>(
        hb, W1T, b1, nullptr, ffb, nullptr, BT, 4096, 1024);
    // ffn2: split-K=4 bf16 partials (pool free again)
    gemm_bf16<128, 4, __bf16, false, false, false, false><<<dim3(8, 32, 4), 256, 0, stream>>>(
        ffb, W2T, nullptr, nullptr, ffp, nullptr, BT, 1024, 4096);
    // reduce partials + b2 + residual(x2) -> out
    reduce_ffn<<<BT, 256, 0, stream>>>(ffp, b2, x2, out);
}

// Round 7
// 366.423 us; speedup vs baseline: 12.8372x; 1.0605x over previous
//
#include <hip/hip_runtime.h>
#include <hip/hip_bf16.h>
#include <math.h>

#define BB 2
#define TT 2048
#define CC 1024
#define NH 16
#define HD 64
#define BT (BB*TT)          // 4096 rows
#define LN_EPS 1e-5f
#define ATT_SCALE 0.03125f  // C^-0.5 (reference scales by full C, not head_size)

typedef __bf16 bf16x8 __attribute__((ext_vector_type(8)));
typedef __bf16 bf16x4 __attribute__((ext_vector_type(4)));
typedef short shortx4 __attribute__((ext_vector_type(4)));
typedef float floatx4 __attribute__((ext_vector_type(4)));

__device__ __forceinline__ void gl_lds16(const __bf16* g, __bf16* l) {
    __builtin_amdgcn_global_load_lds((const __attribute__((address_space(1))) void*)g,
                                     (__attribute__((address_space(3))) void*)l,
                                     16, 0, 0);
}

#define MFMA32(a, b, c) __builtin_amdgcn_mfma_f32_16x16x32_bf16(a, b, c, 0, 0, 0)

#if __has_builtin(__builtin_amdgcn_mfma_f32_16x16x16_bf16)
__device__ __forceinline__ floatx4 mfma16(bf16x4 a, bf16x4 b, floatx4 c) {
    return __builtin_amdgcn_mfma_f32_16x16x16_bf16(a, b, c, 0, 0, 0);
}
#else
__device__ __forceinline__ floatx4 mfma16(bf16x4 a, bf16x4 b, floatx4 c) {
    return __builtin_amdgcn_mfma_f32_16x16x16bf16_1k(
        __builtin_bit_cast(shortx4, a), __builtin_bit_cast(shortx4, b), c, 0, 0, 0);
}
#endif

// XCD-aware block remap for GEMMs (see round-6 notes).
__device__ __forceinline__ void swizzle_xcd(int& xb, int& yb, int& zb) {
    int nx = gridDim.x, ny = gridDim.y;
    int total = nx * ny * (int)gridDim.z;
    int lin = blockIdx.x + nx * (blockIdx.y + ny * blockIdx.z);
    int c = lin & 7, s = lin >> 3;
    int idx = c * (total >> 3) + s;
    xb = idx % nx;
    yb = (idx / nx) % ny;
    zb = idx / (nx * ny);
}

// ---------------------------------------------------------------------------
// LayerNorm: fp32 in -> bf16 out. One block (256 thr) per row.
// ---------------------------------------------------------------------------
__global__ __launch_bounds__(256) void ln_kernel(const float* __restrict__ x,
                                                 const float* __restrict__ g,
                                                 const float* __restrict__ b,
                                                 __bf16* __restrict__ out) {
    int row = blockIdx.x;
    const float4* xr = (const float4*)(x + (size_t)row * CC);
    float4 v = xr[threadIdx.x];
    float s  = v.x + v.y + v.z + v.w;
    float ss = v.x*v.x + v.y*v.y + v.z*v.z + v.w*v.w;
    #pragma unroll
    for (int off = 32; off; off >>= 1) {
        s  += __shfl_down(s, off);
        ss += __shfl_down(ss, off);
    }
    __shared__ float rs_[4], rss_[4];
    __shared__ float mu_s, inv_s;
    int lane = threadIdx.x & 63, wid = threadIdx.x >> 6;
    if (lane == 0) { rs_[wid] = s; rss_[wid] = ss; }
    __syncthreads();
    if (threadIdx.x == 0) {
        float S  = rs_[0] + rs_[1] + rs_[2] + rs_[3];
        float SS = rss_[0] + rss_[1] + rss_[2] + rss_[3];
        float mu  = S * (1.0f / CC);
        float var = SS * (1.0f / CC) - mu * mu;
        mu_s  = mu;
        inv_s = rsqrtf(var + LN_EPS);
    }
    __syncthreads();
    float mu = mu_s, inv = inv_s;
    float4 gv = ((const float4*)g)[threadIdx.x];
    float4 bv = ((const float4*)b)[threadIdx.x];
    bf16x4 o;
    o[0] = (__bf16)((v.x - mu) * inv * gv.x + bv.x);
    o[1] = (__bf16)((v.y - mu) * inv * gv.y + bv.y);
    o[2] = (__bf16)((v.z - mu) * inv * gv.z + bv.z);
    o[3] = (__bf16)((v.w - mu) * inv * gv.w + bv.w);
    *(bf16x4*)(out + (size_t)row * CC + threadIdx.x * 4) = o;
}

// ---------------------------------------------------------------------------
// Reduce 2 bf16 split-K partials + bias + residual -> x2 (fp32), then LN ->
// hb (bf16). Fuses the Wo epilogue with ln2. One block per row.
// ---------------------------------------------------------------------------
__global__ __launch_bounds__(256) void reduce_wo_ln(const __bf16* __restrict__ P,
                                                    const float* __restrict__ bo,
                                                    const float* __restrict__ x,
                                                    const float* __restrict__ g2,
                                                    const float* __restrict__ be2,
                                                    float* __restrict__ x2,
                                                    __bf16* __restrict__ hb) {
    int row = blockIdx.x;
    int c = threadIdx.x * 4;
    bf16x4 a0 = *(const bf16x4*)(P + (size_t)row * CC + c);
    bf16x4 a1 = *(const bf16x4*)(P + (size_t)BT * CC + (size_t)row * CC + c);
    float4 xb = *(const float4*)(x + (size_t)row * CC + c);
    float4 bb = *(const float4*)(bo + c);
    float4 v;
    v.x = xb.x + bb.x + (float)a0[0] + (float)a1[0];
    v.y = xb.y + bb.y + (float)a0[1] + (float)a1[1];
    v.z = xb.z + bb.z + (float)a0[2] + (float)a1[2];
    v.w = xb.w + bb.w + (float)a0[3] + (float)a1[3];
    *(float4*)(x2 + (size_t)row * CC + c) = v;

    float s  = v.x + v.y + v.z + v.w;
    float ss = v.x*v.x + v.y*v.y + v.z*v.z + v.w*v.w;
    #pragma unroll
    for (int off = 32; off; off >>= 1) {
        s  += __shfl_down(s, off);
        ss += __shfl_down(ss, off);
    }
    __shared__ float rs_[4], rss_[4];
    __shared__ float mu_s, inv_s;
    int lane = threadIdx.x & 63, wid = threadIdx.x >> 6;
    if (lane == 0) { rs_[wid] = s; rss_[wid] = ss; }
    __syncthreads();
    if (threadIdx.x == 0) {
        float S  = rs_[0] + rs_[1] + rs_[2] + rs_[3];
        float SS = rss_[0] + rss_[1] + rss_[2] + rss_[3];
        float mu  = S * (1.0f / CC);
        float var = SS * (1.0f / CC) - mu * mu;
        mu_s  = mu;
        inv_s = rsqrtf(var + LN_EPS);
    }
    __syncthreads();
    float mu = mu_s, inv = inv_s;
    float4 gv = ((const float4*)g2)[threadIdx.x];
    float4 bv = ((const float4*)be2)[threadIdx.x];
    bf16x4 o;
    o[0] = (__bf16)((v.x - mu) * inv * gv.x + bv.x);
    o[1] = (__bf16)((v.y - mu) * inv * gv.y + bv.y);
    o[2] = (__bf16)((v.z - mu) * inv * gv.z + bv.z);
    o[3] = (__bf16)((v.w - mu) * inv * gv.w + bv.w);
    *(bf16x4*)(hb + (size_t)row * CC + c) = o;
}

// ---------------------------------------------------------------------------
// Reduce 4 bf16 split-K partials + bias + residual(x2) -> out (fp32).
// ---------------------------------------------------------------------------
__global__ __launch_bounds__(256) void reduce_ffn(const __bf16* __restrict__ P,
                                                  const float* __restrict__ b2,
                                                  const float* __restrict__ x2,
                                                  float* __restrict__ out) {
    int row = blockIdx.x;
    int c = threadIdx.x * 4;
    const size_t S = (size_t)BT * CC;
    float4 v = *(const float4*)(x2 + (size_t)row * CC + c);
    float4 bb = *(const float4*)(b2 + c);
    v.x += bb.x; v.y += bb.y; v.z += bb.z; v.w += bb.w;
    #pragma unroll
    for (int z = 0; z < 4; ++z) {
        bf16x4 a = *(const bf16x4*)(P + z * S + (size_t)row * CC + c);
        v.x += (float)a[0]; v.y += (float)a[1]; v.z += (float)a[2]; v.w += (float)a[3];
    }
    *(float4*)(out + (size_t)row * CC + c) = v;
}

// ---------------------------------------------------------------------------
// All weight transposes fused in one launch. 32x32 tiles; block-uniform branch.
// ---------------------------------------------------------------------------
__global__ __launch_bounds__(256) void transpose_all(
        const float* __restrict__ Wq, const float* __restrict__ Wk,
        const float* __restrict__ Wv, const float* __restrict__ Wo,
        const float* __restrict__ W1, const float* __restrict__ W2,
        __bf16* __restrict__ WqkvT, __bf16* __restrict__ WoT,
        __bf16* __restrict__ W1T, __bf16* __restrict__ W2T) {
    int idx = blockIdx.x;
    const float* src; __bf16* dst; int K, N, tn, tk;
    if (idx < 3072) {                      // Wq|Wk|Wv -> WqkvT (stacked)
        int wsel = idx >> 10, local = idx & 1023;
        src = (wsel == 0) ? Wq : (wsel == 1 ? Wk : Wv);
        dst = WqkvT + (size_t)wsel * 1024 * 1024;
        K = 1024; N = 1024; tn = local & 31; tk = local >> 5;
    } else if (idx < 4096) {
        int local = idx - 3072;
        src = Wo; dst = WoT; K = 1024; N = 1024; tn = local & 31; tk = local >> 5;
    } else if (idx < 8192) {
        int local = idx - 4096;
        src = W1; dst = W1T; K = 1024; N = 4096; tn = local & 127; tk = local >> 7;
    } else {
        int local = idx - 8192;
        src = W2; dst = W2T; K = 4096; N = 1024; tn = local & 31; tk = local >> 5;
    }
    __shared__ float t[32][33];
    int n0 = tn * 32, k0 = tk * 32;
    int tx = threadIdx.x & 31, ty = threadIdx.x >> 5;
    #pragma unroll
    for (int r = ty; r < 32; r += 8)
        t[r][tx] = src[(size_t)(k0 + r) * N + n0 + tx];
    __syncthreads();
    #pragma unroll
    for (int r = ty; r < 32; r += 8)
        dst[(size_t)(n0 + r) * K + k0 + tx] = (__bf16)t[tx][r];
}

// ---------------------------------------------------------------------------
// bf16 MFMA GEMM: C[M,N] = A[M,K] @ Bt[N,K]^T.  (unchanged from round 6)
// ---------------------------------------------------------------------------
template<int NT, int SK, typename OT, bool BIAS, bool RELU, bool RES, bool VSPLIT>
__global__ __launch_bounds__(256) void gemm_bf16(const __bf16* __restrict__ A,
                                                 const __bf16* __restrict__ Bt,
                                                 const float* __restrict__ bias,
                                                 const float* __restrict__ res,
                                                 OT* __restrict__ C,
                                                 __bf16* __restrict__ vt,
                                                 int M, int N, int K) {
    constexpr int JN = NT / 32;
    __shared__ __bf16 As[128 * 32];
    __shared__ __bf16 Bs[NT * 32];
    int bx, by, bz;
    swizzle_xcd(bx, by, bz);
    const int tid = threadIdx.x;
    const int l = tid & 63, w = tid >> 6;
    const int m = l & 15, g = l >> 4;
    const int wm = w >> 1, wn = w & 1;
    const int m0 = by * 128, n0 = bx * NT;
    const int Keff = K / SK;
    const int kbase = (SK > 1) ? bz * Keff : 0;

    const int srow = w * 16 + (l >> 2);
    const int skof = (l & 3) * 8;
    const __bf16* ga = A  + (size_t)(m0 + srow) * K + kbase + skof;
    const __bf16* gb = Bt + (size_t)(n0 + srow) * K + kbase + skof;
    __bf16* la0 = As + w * 512;
    __bf16* lb0 = Bs + w * 512;

    floatx4 acc[4][JN];
    #pragma unroll
    for (int i = 0; i < 4; ++i)
        #pragma unroll
        for (int j = 0; j < JN; ++j) {
            floatx4 z = {0.f, 0.f, 0.f, 0.f};
            acc[i][j] = z;
        }

    for (int kt = 0; kt < Keff; kt += 32) {
        __syncthreads();
        gl_lds16(ga,                  la0);
        gl_lds16(ga + (size_t)64 * K, la0 + 2048);
        gl_lds16(gb,                  lb0);
        if (NT == 128)
            gl_lds16(gb + (size_t)64 * K, lb0 + 2048);
        ga += 32; gb += 32;
        __syncthreads();

        bf16x8 af[4], bfr[JN];
        #pragma unroll
        for (int i = 0; i < 4; ++i)
            af[i] = *(const bf16x8*)&As[(wm * 64 + i * 16 + m) * 32 + g * 8];
        #pragma unroll
        for (int j = 0; j < JN; ++j)
            bfr[j] = *(const bf16x8*)&Bs[(wn * (NT / 2) + j * 16 + m) * 32 + g * 8];
        #pragma unroll
        for (int i = 0; i < 4; ++i)
            #pragma unroll
            for (int j = 0; j < JN; ++j)
                acc[i][j] = MFMA32(af[i], bfr[j], acc[i][j]);
    }

    if (SK > 1) {
        __bf16* P = (__bf16*)C + (size_t)bz * M * N;
        #pragma unroll
        for (int i = 0; i < 4; ++i) {
            int row = m0 + wm * 64 + i * 16 + g * 4;
            #pragma unroll
            for (int j = 0; j < JN; ++j) {
                int col = n0 + wn * (NT / 2) + j * 16 + m;
                #pragma unroll
                for (int r = 0; r < 4; ++r)
                    P[(size_t)(row + r) * N + col] = (__bf16)acc[i][j][r];
            }
        }
    } else if (VSPLIT && n0 >= 2048) {
        #pragma unroll
        for (int i = 0; i < 4; ++i) {
            int row = m0 + wm * 64 + i * 16 + g * 4;
            int bb = row >> 11, t0 = row & 2047;
            #pragma unroll
            for (int j = 0; j < JN; ++j) {
                int cv = n0 + wn * (NT / 2) + j * 16 + m - 2048;
                bf16x4 o;
                #pragma unroll
                for (int r = 0; r < 4; ++r) o[r] = (__bf16)acc[i][j][r];
                *(bf16x4*)(vt + ((size_t)(bb * NH + (cv >> 6)) * HD + (cv & 63)) * 2048 + t0) = o;
            }
        }
    } else {
        #pragma unroll
        for (int i = 0; i < 4; ++i) {
            int row = m0 + wm * 64 + i * 16 + g * 4;
            #pragma unroll
            for (int j = 0; j < JN; ++j) {
                int col = n0 + wn * (NT / 2) + j * 16 + m;
                float bv = BIAS ? bias[col] : 0.0f;
                #pragma unroll
                for (int r = 0; r < 4; ++r) {
                    float vo = acc[i][j][r] + bv;
                    if (RELU) vo = fmaxf(vo, 0.0f);
                    if (RES)  vo += res[(size_t)(row + r) * N + col];
                    C[(size_t)(row + r) * N + col] = (OT)vo;
                }
            }
        }
    }
}

// ---------------------------------------------------------------------------
// Flash attention v3. S^T orientation (round-4). New in round 7:
//  - flat 512-block grid with makespan pairing: blocks lin and lin+256 land
//    on the same CU under round-robin dispatch; they get q-tiles q0 and
//    15-q0, so every CU does exactly 17 k-iterations.
//  - XOR-swizzled LDS layouts (swizzle carried by the gather side of
//    global_load_lds): Ks phys chunk = g ^ ((key>>1)&3)  -> conflict-free
//    b128 reads; Vt3 phys half = half ^ ((d>>2)&1) -> conflict-free b64.
//  - max-free softmax: scale=1/32 bounds |S*scale| << 88, so exp without
//    running-max is safe; no alpha rescale, l reduced cross-lane once at end.
// ---------------------------------------------------------------------------
__global__ __launch_bounds__(256, 2) void attn_mfma3(const __bf16* __restrict__ qkv,
                                                     const __bf16* __restrict__ vt,
                                                     __bf16* __restrict__ att) {
    const int lin = blockIdx.x;
    const int half = lin >> 8, pid = lin & 255;
    const int q0 = pid & 7, h = (pid >> 3) & 15, b = pid >> 7;
    const int qt = half ? 15 - q0 : q0;

    const int tid = threadIdx.x;
    const int l = tid & 63, w = tid >> 6;
    const int m = l & 15, g = l >> 4;

    __shared__ __bf16 Ks[2][128][32];   // [d-half][key][32 d] (chunk-swizzled)
    __shared__ __bf16 Vt3[8][64][16];   // [key/16][d][16 keys] (half-swizzled)

    const __bf16* qp = qkv + (size_t)b * TT * 3072 + h * HD;
    const __bf16* kp = qp + 1024;
    const __bf16* vh = vt + (size_t)(b * NH + h) * HD * 2048;

    bf16x8 qb[2][2];
    #pragma unroll
    for (int nt = 0; nt < 2; ++nt) {
        int qrow = qt * 128 + w * 32 + nt * 16 + m;
        qb[nt][0] = *(const bf16x8*)(qp + (size_t)qrow * 3072 + g * 8);
        qb[nt][1] = *(const bf16x8*)(qp + (size_t)qrow * 3072 + 32 + g * 8);
    }

    floatx4 O[2][4];
    float l_s[2] = {0.0f, 0.0f};
    #pragma unroll
    for (int nt = 0; nt < 2; ++nt)
        #pragma unroll
        for (int jd = 0; jd < 4; ++jd) {
            floatx4 z = {0.f, 0.f, 0.f, 0.f};
            O[nt][jd] = z;
        }

    for (int kt = 0; kt <= qt; ++kt) {
        __syncthreads();
        // K tile: lane's logical d-chunk = (l&3) ^ ((l>>3)&3)  (key=l>>2)
        #pragma unroll
        for (int c = 0; c < 4; ++c) {
            int idx = w * 4 + c;
            int dh = idx >> 3, k16 = idx & 7;
            gl_lds16(kp + (size_t)(kt * 128 + k16 * 16 + (l >> 2)) * 3072
                        + dh * 32 + (((l & 3) ^ ((l >> 3) & 3)) * 8),
                     (__bf16*)Ks + dh * 4096 + k16 * 512);
        }
        // V^T tile: lane's logical key-half = (l&1) ^ ((l>>3)&1)  (d=l>>1)
        #pragma unroll
        for (int c = 0; c < 4; ++c) {
            int idx = w * 4 + c;
            int jt = idx >> 1, dhf = idx & 1;
            gl_lds16(vh + (size_t)(dhf * 32 + (l >> 1)) * 2048 + kt * 128
                        + jt * 16 + (((l & 1) ^ ((l >> 3) & 1)) * 8),
                     (__bf16*)Vt3 + jt * 1024 + dhf * 512);
        }
        __syncthreads();

        // S^T[key][qrow] = K·Q^T
        floatx4 S[2][8];
        #pragma unroll
        for (int jt = 0; jt < 8; ++jt) {
            int co = (g ^ ((m >> 1) & 3)) * 8;
            bf16x8 kf0 = *(const bf16x8*)&Ks[0][jt * 16 + m][co];
            bf16x8 kf1 = *(const bf16x8*)&Ks[1][jt * 16 + m][co];
            #pragma unroll
            for (int nt = 0; nt < 2; ++nt) {
                floatx4 z = {0.f, 0.f, 0.f, 0.f};
                z = MFMA32(kf0, qb[nt][0], z);
                S[nt][jt] = MFMA32(kf1, qb[nt][1], z);
            }
        }

        // max-free softmax: p = exp(S*scale); per-lane partial l only.
        bf16x4 pv[2][8];
        const bool last = (kt == qt);
        #pragma unroll
        for (int nt = 0; nt < 2; ++nt) {
            if (last) {
                int qr = w * 32 + nt * 16 + m;
                #pragma unroll
                for (int jt = 0; jt < 8; ++jt)
                    #pragma unroll
                    for (int r = 0; r < 4; ++r)
                        if (jt * 16 + g * 4 + r > qr) S[nt][jt][r] = -1e30f;
            }
            float ls = 0.0f;
            #pragma unroll
            for (int jt = 0; jt < 8; ++jt) {
                bf16x4 t;
                #pragma unroll
                for (int r = 0; r < 4; ++r) {
                    float p = __expf(S[nt][jt][r] * ATT_SCALE);
                    ls += p;
                    t[r] = (__bf16)p;
                }
                pv[nt][jt] = t;
            }
            l_s[nt] += ls;
        }

        // O^T[d][qrow] += V^T · P
        #pragma unroll
        for (int jt = 0; jt < 8; ++jt)
            #pragma unroll
            for (int jd = 0; jd < 4; ++jd) {
                bf16x4 vf = *(const bf16x4*)&Vt3[jt][jd * 16 + m]
                                [((g >> 1) ^ ((m >> 2) & 1)) * 8 + (g & 1) * 4];
                #pragma unroll
                for (int nt = 0; nt < 2; ++nt)
                    O[nt][jd] = mfma16(vf, pv[nt][jt], O[nt][jd]);
            }
    }

    // epilogue: reduce l across the 4 g-groups, normalize, store
    #pragma unroll
    for (int nt = 0; nt < 2; ++nt) {
        float lsum = l_s[nt];
        lsum += __shfl_xor(lsum, 16, 64);
        lsum += __shfl_xor(lsum, 32, 64);
        float inv = 1.0f / lsum;
        int qrow = qt * 128 + w * 32 + nt * 16 + m;
        #pragma unroll
        for (int jd = 0; jd < 4; ++jd) {
            bf16x4 o;
            #pragma unroll
            for (int r = 0; r < 4; ++r) o[r] = (__bf16)(O[nt][jd][r] * inv);
            *(bf16x4*)(att + ((size_t)b * TT + qrow) * CC + h * HD + jd * 16 + g * 4) = o;
        }
    }
}

// ---------------------------------------------------------------------------
extern "C" void kernel_launch(void* const* d_in, const int* in_sizes, int n_in,
                              void* d_out, int out_size, void* d_ws, size_t ws_size,
                              hipStream_t stream) {
    const float* x   = (const float*)d_in[0];
    const float* Wq  = (const float*)d_in[1];
    const float* Wk  = (const float*)d_in[2];
    const float* Wv  = (const float*)d_in[3];
    const float* Wo  = (const float*)d_in[4];
    const float* bo  = (const float*)d_in[5];
    const float* W1  = (const float*)d_in[6];
    const float* b1  = (const float*)d_in[7];
    const float* W2  = (const float*)d_in[8];
    const float* b2  = (const float*)d_in[9];
    const float* g1  = (const float*)d_in[10];
    const float* be1 = (const float*)d_in[11];
    const float* g2  = (const float*)d_in[12];
    const float* be2 = (const float*)d_in[13];
    float* out = (float*)d_out;

    char* p = (char*)d_ws;
    char*   pool  = p;          p += (size_t)32 * 1024 * 1024;
    __bf16* qkvb  = (__bf16*)pool;
    __bf16* vtb   = (__bf16*)(pool + (size_t)BT * 3072 * 2);
    __bf16* wop   = (__bf16*)pool;     // 2 x [BT][CC] bf16 partials
    __bf16* ffp   = (__bf16*)pool;     // 4 x [BT][CC] bf16 partials
    __bf16* attb  = (__bf16*)p; p += (size_t)BT * CC * 2;
    __bf16* hb    = (__bf16*)p; p += (size_t)BT * CC * 2;
    float*  x2    = (float*)p;  p += (size_t)BT * CC * 4;
    __bf16* ffb   = (__bf16*)p; p += (size_t)BT * 4096 * 2;
    __bf16* WqkvT = (__bf16*)p; p += (size_t)3072 * 1024 * 2;
    __bf16* WoT   = (__bf16*)p; p += (size_t)1024 * 1024 * 2;
    __bf16* W1T   = (__bf16*)p; p += (size_t)4096 * 1024 * 2;
    __bf16* W2T   = (__bf16*)p; p += (size_t)1024 * 4096 * 2;

    transpose_all<<<12288, 256, 0, stream>>>(Wq, Wk, Wv, Wo, W1, W2,
                                             WqkvT, WoT, W1T, W2T);
    ln_kernel<<<BT, 256, 0, stream>>>(x, g1, be1, hb);
    gemm_bf16<128, 1, __bf16, false, false, false, true><<<dim3(24, 32), 256, 0, stream>>>(
        hb, WqkvT, nullptr, nullptr, qkvb, vtb, BT, 3072, 1024);
    attn_mfma3<<<512, 256, 0, stream>>>(qkvb, vtb, attb);
    gemm_bf16<64, 2, __bf16, false, false, false, false><<<dim3(16, 32, 2), 256, 0, stream>>>(
        attb, WoT, nullptr, nullptr, wop, nullptr, BT, 1024, 1024);
    reduce_wo_ln<<<BT, 256, 0, stream>>>(wop, bo, x, g2, be2, x2, hb);
    gemm_bf16<128, 1, __bf16, true, true, false, false><<<dim3(32, 32), 256, 0, stream>>>(
        hb, W1T, b1, nullptr, ffb, nullptr, BT, 4096, 1024);
    gemm_bf16<128, 4, __bf16, false, false, false, false><<<dim3(8, 32, 4), 256, 0, stream>>>(
        ffb, W2T, nullptr, nullptr, ffp, nullptr, BT, 1024, 4096);
    reduce_ffn<<<BT, 256, 0, stream>>>(ffp, b2, x2, out);
}

// Round 8
// 335.011 us; speedup vs baseline: 14.0409x; 1.0938x over previous
//
#include <hip/hip_runtime.h>
#include <hip/hip_bf16.h>
#include <math.h>

#define BB 2
#define TT 2048
#define CC 1024
#define NH 16
#define HD 64
#define BT (BB*TT)          // 4096 rows
#define LN_EPS 1e-5f
#define ATT_SCALE 0.03125f  // C^-0.5 (reference scales by full C, not head_size)

typedef __bf16 bf16x8 __attribute__((ext_vector_type(8)));
typedef __bf16 bf16x4 __attribute__((ext_vector_type(4)));
typedef short shortx4 __attribute__((ext_vector_type(4)));
typedef float floatx4 __attribute__((ext_vector_type(4)));

__device__ __forceinline__ void gl_lds16(const __bf16* g, __bf16* l) {
    __builtin_amdgcn_global_load_lds((const __attribute__((address_space(1))) void*)g,
                                     (__attribute__((address_space(3))) void*)l,
                                     16, 0, 0);
}

#define MFMA32(a, b, c) __builtin_amdgcn_mfma_f32_16x16x32_bf16(a, b, c, 0, 0, 0)

#if __has_builtin(__builtin_amdgcn_mfma_f32_16x16x16_bf16)
__device__ __forceinline__ floatx4 mfma16(bf16x4 a, bf16x4 b, floatx4 c) {
    return __builtin_amdgcn_mfma_f32_16x16x16_bf16(a, b, c, 0, 0, 0);
}
#else
__device__ __forceinline__ floatx4 mfma16(bf16x4 a, bf16x4 b, floatx4 c) {
    return __builtin_amdgcn_mfma_f32_16x16x16bf16_1k(
        __builtin_bit_cast(shortx4, a), __builtin_bit_cast(shortx4, b), c, 0, 0, 0);
}
#endif

// XCD-aware block remap for GEMMs (see round-6 notes).
__device__ __forceinline__ void swizzle_xcd(int& xb, int& yb, int& zb) {
    int nx = gridDim.x, ny = gridDim.y;
    int total = nx * ny * (int)gridDim.z;
    int lin = blockIdx.x + nx * (blockIdx.y + ny * blockIdx.z);
    int c = lin & 7, s = lin >> 3;
    int idx = c * (total >> 3) + s;
    xb = idx % nx;
    yb = (idx / nx) % ny;
    zb = idx / (nx * ny);
}

// ---------------------------------------------------------------------------
// Fused: all weight transposes (idx < 12288) + ln1 (idx >= 12288).
// Transpose: W[K][N] fp32 -> Wt[N][K] bf16, 32x32 tiles. LN: one block/row.
// ---------------------------------------------------------------------------
__global__ __launch_bounds__(256) void transpose_ln(
        const float* __restrict__ Wq, const float* __restrict__ Wk,
        const float* __restrict__ Wv, const float* __restrict__ Wo,
        const float* __restrict__ W1, const float* __restrict__ W2,
        __bf16* __restrict__ WqkvT, __bf16* __restrict__ WoT,
        __bf16* __restrict__ W1T, __bf16* __restrict__ W2T,
        const float* __restrict__ x, const float* __restrict__ g1,
        const float* __restrict__ be1, __bf16* __restrict__ hb) {
    __shared__ float t[32][33];
    __shared__ float rs_[4], rss_[4];
    __shared__ float mu_s, inv_s;
    int idx = blockIdx.x;
    if (idx >= 12288) {
        // ---- LayerNorm branch ----
        int row = idx - 12288;
        const float4* xr = (const float4*)(x + (size_t)row * CC);
        float4 v = xr[threadIdx.x];
        float s  = v.x + v.y + v.z + v.w;
        float ss = v.x*v.x + v.y*v.y + v.z*v.z + v.w*v.w;
        #pragma unroll
        for (int off = 32; off; off >>= 1) {
            s  += __shfl_down(s, off);
            ss += __shfl_down(ss, off);
        }
        int lane = threadIdx.x & 63, wid = threadIdx.x >> 6;
        if (lane == 0) { rs_[wid] = s; rss_[wid] = ss; }
        __syncthreads();
        if (threadIdx.x == 0) {
            float S  = rs_[0] + rs_[1] + rs_[2] + rs_[3];
            float SS = rss_[0] + rss_[1] + rss_[2] + rss_[3];
            float mu  = S * (1.0f / CC);
            float var = SS * (1.0f / CC) - mu * mu;
            mu_s  = mu;
            inv_s = rsqrtf(var + LN_EPS);
        }
        __syncthreads();
        float mu = mu_s, inv = inv_s;
        float4 gv = ((const float4*)g1)[threadIdx.x];
        float4 bv = ((const float4*)be1)[threadIdx.x];
        bf16x4 o;
        o[0] = (__bf16)((v.x - mu) * inv * gv.x + bv.x);
        o[1] = (__bf16)((v.y - mu) * inv * gv.y + bv.y);
        o[2] = (__bf16)((v.z - mu) * inv * gv.z + bv.z);
        o[3] = (__bf16)((v.w - mu) * inv * gv.w + bv.w);
        *(bf16x4*)(hb + (size_t)row * CC + threadIdx.x * 4) = o;
        return;
    }
    // ---- transpose branch ----
    const float* src; __bf16* dst; int K, N, tn, tk;
    if (idx < 3072) {
        int wsel = idx >> 10, local = idx & 1023;
        src = (wsel == 0) ? Wq : (wsel == 1 ? Wk : Wv);
        dst = WqkvT + (size_t)wsel * 1024 * 1024;
        K = 1024; N = 1024; tn = local & 31; tk = local >> 5;
    } else if (idx < 4096) {
        int local = idx - 3072;
        src = Wo; dst = WoT; K = 1024; N = 1024; tn = local & 31; tk = local >> 5;
    } else if (idx < 8192) {
        int local = idx - 4096;
        src = W1; dst = W1T; K = 1024; N = 4096; tn = local & 127; tk = local >> 7;
    } else {
        int local = idx - 8192;
        src = W2; dst = W2T; K = 4096; N = 1024; tn = local & 31; tk = local >> 5;
    }
    int n0 = tn * 32, k0 = tk * 32;
    int tx = threadIdx.x & 31, ty = threadIdx.x >> 5;
    #pragma unroll
    for (int r = ty; r < 32; r += 8)
        t[r][tx] = src[(size_t)(k0 + r) * N + n0 + tx];
    __syncthreads();
    #pragma unroll
    for (int r = ty; r < 32; r += 8)
        dst[(size_t)(n0 + r) * K + k0 + tx] = (__bf16)t[tx][r];
}

// ---------------------------------------------------------------------------
// Reduce 2 bf16 split-K partials + bias + residual -> x2 (fp32), then LN ->
// hb (bf16). Fuses the Wo epilogue with ln2. One block per row.
// ---------------------------------------------------------------------------
__global__ __launch_bounds__(256) void reduce_wo_ln(const __bf16* __restrict__ P,
                                                    const float* __restrict__ bo,
                                                    const float* __restrict__ x,
                                                    const float* __restrict__ g2,
                                                    const float* __restrict__ be2,
                                                    float* __restrict__ x2,
                                                    __bf16* __restrict__ hb) {
    int row = blockIdx.x;
    int c = threadIdx.x * 4;
    bf16x4 a0 = *(const bf16x4*)(P + (size_t)row * CC + c);
    bf16x4 a1 = *(const bf16x4*)(P + (size_t)BT * CC + (size_t)row * CC + c);
    float4 xb = *(const float4*)(x + (size_t)row * CC + c);
    float4 bb = *(const float4*)(bo + c);
    float4 v;
    v.x = xb.x + bb.x + (float)a0[0] + (float)a1[0];
    v.y = xb.y + bb.y + (float)a0[1] + (float)a1[1];
    v.z = xb.z + bb.z + (float)a0[2] + (float)a1[2];
    v.w = xb.w + bb.w + (float)a0[3] + (float)a1[3];
    *(float4*)(x2 + (size_t)row * CC + c) = v;

    float s  = v.x + v.y + v.z + v.w;
    float ss = v.x*v.x + v.y*v.y + v.z*v.z + v.w*v.w;
    #pragma unroll
    for (int off = 32; off; off >>= 1) {
        s  += __shfl_down(s, off);
        ss += __shfl_down(ss, off);
    }
    __shared__ float rs_[4], rss_[4];
    __shared__ float mu_s, inv_s;
    int lane = threadIdx.x & 63, wid = threadIdx.x >> 6;
    if (lane == 0) { rs_[wid] = s; rss_[wid] = ss; }
    __syncthreads();
    if (threadIdx.x == 0) {
        float S  = rs_[0] + rs_[1] + rs_[2] + rs_[3];
        float SS = rss_[0] + rss_[1] + rss_[2] + rss_[3];
        float mu  = S * (1.0f / CC);
        float var = SS * (1.0f / CC) - mu * mu;
        mu_s  = mu;
        inv_s = rsqrtf(var + LN_EPS);
    }
    __syncthreads();
    float mu = mu_s, inv = inv_s;
    float4 gv = ((const float4*)g2)[threadIdx.x];
    float4 bv = ((const float4*)be2)[threadIdx.x];
    bf16x4 o;
    o[0] = (__bf16)((v.x - mu) * inv * gv.x + bv.x);
    o[1] = (__bf16)((v.y - mu) * inv * gv.y + bv.y);
    o[2] = (__bf16)((v.z - mu) * inv * gv.z + bv.z);
    o[3] = (__bf16)((v.w - mu) * inv * gv.w + bv.w);
    *(bf16x4*)(hb + (size_t)row * CC + c) = o;
}

// ---------------------------------------------------------------------------
// Reduce 4 bf16 split-K partials + bias + residual(x2) -> out (fp32).
// ---------------------------------------------------------------------------
__global__ __launch_bounds__(256) void reduce_ffn(const __bf16* __restrict__ P,
                                                  const float* __restrict__ b2,
                                                  const float* __restrict__ x2,
                                                  float* __restrict__ out) {
    int row = blockIdx.x;
    int c = threadIdx.x * 4;
    const size_t S = (size_t)BT * CC;
    float4 v = *(const float4*)(x2 + (size_t)row * CC + c);
    float4 bb = *(const float4*)(b2 + c);
    v.x += bb.x; v.y += bb.y; v.z += bb.z; v.w += bb.w;
    #pragma unroll
    for (int z = 0; z < 4; ++z) {
        bf16x4 a = *(const bf16x4*)(P + z * S + (size_t)row * CC + c);
        v.x += (float)a[0]; v.y += (float)a[1]; v.z += (float)a[2]; v.w += (float)a[3];
    }
    *(float4*)(out + (size_t)row * CC + c) = v;
}

// ---------------------------------------------------------------------------
// bf16 MFMA GEMM v2: C[M,N] = A[M,K] @ Bt[N,K]^T.
// Round-8: BK=64 (32 MFMA per barrier, half the iterations), XOR-swizzled
// LDS chunks (phys = logical ^ (row&7); carried on the GATHER side of
// global_load_lds, read back with chunk = (hf*4+g) ^ (m&7)) -> 2-way max
// bank aliasing (free). Fragments loaded per-k-half to cap VGPR.
// ---------------------------------------------------------------------------
template<int NT, int SK, typename OT, bool BIAS, bool RELU, bool RES, bool VSPLIT>
__global__ __launch_bounds__(256) void gemm_bf16(const __bf16* __restrict__ A,
                                                 const __bf16* __restrict__ Bt,
                                                 const float* __restrict__ bias,
                                                 const float* __restrict__ res,
                                                 OT* __restrict__ C,
                                                 __bf16* __restrict__ vt,
                                                 int M, int N, int K) {
    constexpr int JN = NT / 32;          // 4 or 2
    __shared__ __bf16 As[128 * 64];      // 16 KB
    __shared__ __bf16 Bs[NT * 64];       // 16 or 8 KB
    int bx, by, bz;
    swizzle_xcd(bx, by, bz);
    const int tid = threadIdx.x;
    const int l = tid & 63, w = tid >> 6;
    const int m = l & 15, g = l >> 4;
    const int wm = w >> 1, wn = w & 1;
    const int m0 = by * 128, n0 = bx * NT;
    const int Keff = K / SK;
    const int kbase = (SK > 1) ? bz * Keff : 0;

    // staging: lane covers row (l>>3) of its 8-row group; phys chunk l&7
    // holds logical k-chunk (l&7)^((l>>3)&7).
    const int srow = l >> 3;
    const int sko  = ((l & 7) ^ ((l >> 3) & 7)) * 8;

    floatx4 acc[4][JN];
    #pragma unroll
    for (int i = 0; i < 4; ++i)
        #pragma unroll
        for (int j = 0; j < JN; ++j) {
            floatx4 z = {0.f, 0.f, 0.f, 0.f};
            acc[i][j] = z;
        }

    for (int kt = 0; kt < Keff; kt += 64) {
        __syncthreads();
        #pragma unroll
        for (int c = 0; c < 4; ++c) {
            int idx = w * 4 + c;
            gl_lds16(A + (size_t)(m0 + idx * 8 + srow) * K + kbase + kt + sko,
                     As + idx * 512);
        }
        #pragma unroll
        for (int c = 0; c < JN; ++c) {
            int idx = w * JN + c;
            gl_lds16(Bt + (size_t)(n0 + idx * 8 + srow) * K + kbase + kt + sko,
                     Bs + idx * 512);
        }
        __syncthreads();

        #pragma unroll
        for (int hf = 0; hf < 2; ++hf) {
            const int co = (((hf * 4 + g) ^ (m & 7)) * 8);
            bf16x8 af[4], bfr[JN];
            #pragma unroll
            for (int i = 0; i < 4; ++i)
                af[i] = *(const bf16x8*)&As[(wm * 64 + i * 16 + m) * 64 + co];
            #pragma unroll
            for (int j = 0; j < JN; ++j)
                bfr[j] = *(const bf16x8*)&Bs[(wn * (NT / 2) + j * 16 + m) * 64 + co];
            #pragma unroll
            for (int i = 0; i < 4; ++i)
                #pragma unroll
                for (int j = 0; j < JN; ++j)
                    acc[i][j] = MFMA32(af[i], bfr[j], acc[i][j]);
        }
    }

    if (SK > 1) {
        __bf16* P = (__bf16*)C + (size_t)bz * M * N;
        #pragma unroll
        for (int i = 0; i < 4; ++i) {
            int row = m0 + wm * 64 + i * 16 + g * 4;
            #pragma unroll
            for (int j = 0; j < JN; ++j) {
                int col = n0 + wn * (NT / 2) + j * 16 + m;
                #pragma unroll
                for (int r = 0; r < 4; ++r)
                    P[(size_t)(row + r) * N + col] = (__bf16)acc[i][j][r];
            }
        }
    } else if (VSPLIT && n0 >= 2048) {
        #pragma unroll
        for (int i = 0; i < 4; ++i) {
            int row = m0 + wm * 64 + i * 16 + g * 4;
            int bb = row >> 11, t0 = row & 2047;
            #pragma unroll
            for (int j = 0; j < JN; ++j) {
                int cv = n0 + wn * (NT / 2) + j * 16 + m - 2048;
                bf16x4 o;
                #pragma unroll
                for (int r = 0; r < 4; ++r) o[r] = (__bf16)acc[i][j][r];
                *(bf16x4*)(vt + ((size_t)(bb * NH + (cv >> 6)) * HD + (cv & 63)) * 2048 + t0) = o;
            }
        }
    } else {
        #pragma unroll
        for (int i = 0; i < 4; ++i) {
            int row = m0 + wm * 64 + i * 16 + g * 4;
            #pragma unroll
            for (int j = 0; j < JN; ++j) {
                int col = n0 + wn * (NT / 2) + j * 16 + m;
                float bv = BIAS ? bias[col] : 0.0f;
                #pragma unroll
                for (int r = 0; r < 4; ++r) {
                    float vo = acc[i][j][r] + bv;
                    if (RELU) vo = fmaxf(vo, 0.0f);
                    if (RES)  vo += res[(size_t)(row + r) * N + col];
                    C[(size_t)(row + r) * N + col] = (OT)vo;
                }
            }
        }
    }
}

// ---------------------------------------------------------------------------
// Flash attention v3 (unchanged from round 7): S^T orientation, makespan
// pairing, XOR-swizzled LDS, max-free softmax.
// ---------------------------------------------------------------------------
__global__ __launch_bounds__(256, 2) void attn_mfma3(const __bf16* __restrict__ qkv,
                                                     const __bf16* __restrict__ vt,
                                                     __bf16* __restrict__ att) {
    const int lin = blockIdx.x;
    const int half = lin >> 8, pid = lin & 255;
    const int q0 = pid & 7, h = (pid >> 3) & 15, b = pid >> 7;
    const int qt = half ? 15 - q0 : q0;

    const int tid = threadIdx.x;
    const int l = tid & 63, w = tid >> 6;
    const int m = l & 15, g = l >> 4;

    __shared__ __bf16 Ks[2][128][32];
    __shared__ __bf16 Vt3[8][64][16];

    const __bf16* qp = qkv + (size_t)b * TT * 3072 + h * HD;
    const __bf16* kp = qp + 1024;
    const __bf16* vh = vt + (size_t)(b * NH + h) * HD * 2048;

    bf16x8 qb[2][2];
    #pragma unroll
    for (int nt = 0; nt < 2; ++nt) {
        int qrow = qt * 128 + w * 32 + nt * 16 + m;
        qb[nt][0] = *(const bf16x8*)(qp + (size_t)qrow * 3072 + g * 8);
        qb[nt][1] = *(const bf16x8*)(qp + (size_t)qrow * 3072 + 32 + g * 8);
    }

    floatx4 O[2][4];
    float l_s[2] = {0.0f, 0.0f};
    #pragma unroll
    for (int nt = 0; nt < 2; ++nt)
        #pragma unroll
        for (int jd = 0; jd < 4; ++jd) {
            floatx4 z = {0.f, 0.f, 0.f, 0.f};
            O[nt][jd] = z;
        }

    for (int kt = 0; kt <= qt; ++kt) {
        __syncthreads();
        #pragma unroll
        for (int c = 0; c < 4; ++c) {
            int idx = w * 4 + c;
            int dh = idx >> 3, k16 = idx & 7;
            gl_lds16(kp + (size_t)(kt * 128 + k16 * 16 + (l >> 2)) * 3072
                        + dh * 32 + (((l & 3) ^ ((l >> 3) & 3)) * 8),
                     (__bf16*)Ks + dh * 4096 + k16 * 512);
        }
        #pragma unroll
        for (int c = 0; c < 4; ++c) {
            int idx = w * 4 + c;
            int jt = idx >> 1, dhf = idx & 1;
            gl_lds16(vh + (size_t)(dhf * 32 + (l >> 1)) * 2048 + kt * 128
                        + jt * 16 + (((l & 1) ^ ((l >> 3) & 1)) * 8),
                     (__bf16*)Vt3 + jt * 1024 + dhf * 512);
        }
        __syncthreads();

        floatx4 S[2][8];
        #pragma unroll
        for (int jt = 0; jt < 8; ++jt) {
            int co = (g ^ ((m >> 1) & 3)) * 8;
            bf16x8 kf0 = *(const bf16x8*)&Ks[0][jt * 16 + m][co];
            bf16x8 kf1 = *(const bf16x8*)&Ks[1][jt * 16 + m][co];
            #pragma unroll
            for (int nt = 0; nt < 2; ++nt) {
                floatx4 z = {0.f, 0.f, 0.f, 0.f};
                z = MFMA32(kf0, qb[nt][0], z);
                S[nt][jt] = MFMA32(kf1, qb[nt][1], z);
            }
        }

        bf16x4 pv[2][8];
        const bool last = (kt == qt);
        #pragma unroll
        for (int nt = 0; nt < 2; ++nt) {
            if (last) {
                int qr = w * 32 + nt * 16 + m;
                #pragma unroll
                for (int jt = 0; jt < 8; ++jt)
                    #pragma unroll
                    for (int r = 0; r < 4; ++r)
                        if (jt * 16 + g * 4 + r > qr) S[nt][jt][r] = -1e30f;
            }
            float ls = 0.0f;
            #pragma unroll
            for (int jt = 0; jt < 8; ++jt) {
                bf16x4 t;
                #pragma unroll
                for (int r = 0; r < 4; ++r) {
                    float p = __expf(S[nt][jt][r] * ATT_SCALE);
                    ls += p;
                    t[r] = (__bf16)p;
                }
                pv[nt][jt] = t;
            }
            l_s[nt] += ls;
        }

        #pragma unroll
        for (int jt = 0; jt < 8; ++jt)
            #pragma unroll
            for (int jd = 0; jd < 4; ++jd) {
                bf16x4 vf = *(const bf16x4*)&Vt3[jt][jd * 16 + m]
                                [((g >> 1) ^ ((m >> 2) & 1)) * 8 + (g & 1) * 4];
                #pragma unroll
                for (int nt = 0; nt < 2; ++nt)
                    O[nt][jd] = mfma16(vf, pv[nt][jt], O[nt][jd]);
            }
    }

    #pragma unroll
    for (int nt = 0; nt < 2; ++nt) {
        float lsum = l_s[nt];
        lsum += __shfl_xor(lsum, 16, 64);
        lsum += __shfl_xor(lsum, 32, 64);
        float inv = 1.0f / lsum;
        int qrow = qt * 128 + w * 32 + nt * 16 + m;
        #pragma unroll
        for (int jd = 0; jd < 4; ++jd) {
            bf16x4 o;
            #pragma unroll
            for (int r = 0; r < 4; ++r) o[r] = (__bf16)(O[nt][jd][r] * inv);
            *(bf16x4*)(att + ((size_t)b * TT + qrow) * CC + h * HD + jd * 16 + g * 4) = o;
        }
    }
}

// ---------------------------------------------------------------------------
extern "C" void kernel_launch(void* const* d_in, const int* in_sizes, int n_in,
                              void* d_out, int out_size, void* d_ws, size_t ws_size,
                              hipStream_t stream) {
    const float* x   = (const float*)d_in[0];
    const float* Wq  = (const float*)d_in[1];
    const float* Wk  = (const float*)d_in[2];
    const float* Wv  = (const float*)d_in[3];
    const float* Wo  = (const float*)d_in[4];
    const float* bo  = (const float*)d_in[5];
    const float* W1  = (const float*)d_in[6];
    const float* b1  = (const float*)d_in[7];
    const float* W2  = (const float*)d_in[8];
    const float* b2  = (const float*)d_in[9];
    const float* g1  = (const float*)d_in[10];
    const float* be1 = (const float*)d_in[11];
    const float* g2  = (const float*)d_in[12];
    const float* be2 = (const float*)d_in[13];
    float* out = (float*)d_out;

    char* p = (char*)d_ws;
    char*   pool  = p;          p += (size_t)32 * 1024 * 1024;
    __bf16* qkvb  = (__bf16*)pool;
    __bf16* vtb   = (__bf16*)(pool + (size_t)BT * 3072 * 2);
    __bf16* wop   = (__bf16*)pool;     // 2 x [BT][CC] bf16 partials
    __bf16* ffp   = (__bf16*)pool;     // 4 x [BT][CC] bf16 partials
    __bf16* attb  = (__bf16*)p; p += (size_t)BT * CC * 2;
    __bf16* hb    = (__bf16*)p; p += (size_t)BT * CC * 2;
    float*  x2    = (float*)p;  p += (size_t)BT * CC * 4;
    __bf16* ffb   = (__bf16*)p; p += (size_t)BT * 4096 * 2;
    __bf16* WqkvT = (__bf16*)p; p += (size_t)3072 * 1024 * 2;
    __bf16* WoT   = (__bf16*)p; p += (size_t)1024 * 1024 * 2;
    __bf16* W1T   = (__bf16*)p; p += (size_t)4096 * 1024 * 2;
    __bf16* W2T   = (__bf16*)p; p += (size_t)1024 * 4096 * 2;

    // fused weight transposes + ln1
    transpose_ln<<<16384, 256, 0, stream>>>(Wq, Wk, Wv, Wo, W1, W2,
                                            WqkvT, WoT, W1T, W2T,
                                            x, g1, be1, hb);
    // fused QKV projection; V written transposed into vtb
    gemm_bf16<128, 1, __bf16, false, false, false, true><<<dim3(24, 32), 256, 0, stream>>>(
        hb, WqkvT, nullptr, nullptr, qkvb, vtb, BT, 3072, 1024);
    attn_mfma3<<<512, 256, 0, stream>>>(qkvb, vtb, attb);
    // out proj: split-K=2 bf16 partials
    gemm_bf16<64, 2, __bf16, false, false, false, false><<<dim3(16, 32, 2), 256, 0, stream>>>(
        attb, WoT, nullptr, nullptr, wop, nullptr, BT, 1024, 1024);
    reduce_wo_ln<<<BT, 256, 0, stream>>>(wop, bo, x, g2, be2, x2, hb);
    // ffn1 + bias + relu
    gemm_bf16<128, 1, __bf16, true, true, false, false><<<dim3(32, 32), 256, 0, stream>>>(
        hb, W1T, b1, nullptr, ffb, nullptr, BT, 4096, 1024);
    // ffn2: split-K=4 bf16 partials
    gemm_bf16<128, 4, __bf16, false, false, false, false><<<dim3(8, 32, 4), 256, 0, stream>>>(
        ffb, W2T, nullptr, nullptr, ffp, nullptr, BT, 1024, 4096);
    reduce_ffn<<<BT, 256, 0, stream>>>(ffp, b2, x2, out);
}